// Round 13
// baseline (259.623 us; speedup 1.0000x reference)
//
#include <hip/hip_runtime.h>
#include <math.h>

#define NB 8
#define LQ 900
#define DM 256
#define NH 8
#define DH 32
#define NL 4
#define NP 4
#define DFFN 1024
#define LIN 13294
#define NVAL (NB*LIN)      // 106352 rows for value projection
#define MROW (NB*LQ)       // 7200 rows for query-side matmuls
#define GVAL2 3324         // 1662 M-strips(64) x 2 N-halves(128)

// packed-weight segment offsets (shorts)
#define WP_VAL 0
#define WP_Q   65536
#define WP_K   131072
#define WP_V   196608
#define WP_O   262144
#define WP_OFF 327680
#define WP_ATT 393216
#define WP_OUT 425984
#define WP_W1  491520
#define WP_W2  753664
#define WP_TOT 1015808     // = 3968 * 256

typedef __attribute__((ext_vector_type(8))) short bf16x8;
typedef __attribute__((ext_vector_type(4))) float f32x4;

__device__ __forceinline__ unsigned short f2bf(float x) {
  unsigned u = __float_as_uint(x);
  u += 0x7FFFu + ((u >> 16) & 1u);   // round-to-nearest-even
  return (unsigned short)(u >> 16);
}

// ---------------- pack ALL weights: fp32 [k][n] -> bf16 tiled [kt][n][32], pre-swizzled ----------------
__global__ __launch_bounds__(256) void pack_all(
    const float* __restrict__ w_val, const float* __restrict__ wq,
    const float* __restrict__ wk, const float* __restrict__ wv,
    const float* __restrict__ wo, const float* __restrict__ w_off,
    const float* __restrict__ w_att, const float* __restrict__ w_out,
    const float* __restrict__ w1, const float* __restrict__ w2,
    unsigned short* __restrict__ Wp) {
  const int idx = blockIdx.x * 256 + threadIdx.x;
  const float* src; int r, logN;
  if (idx < WP_Q)        { src = w_val; r = idx;          logN = 8; }
  else if (idx < WP_K)   { src = wq;    r = idx - WP_Q;   logN = 8; }
  else if (idx < WP_V)   { src = wk;    r = idx - WP_K;   logN = 8; }
  else if (idx < WP_O)   { src = wv;    r = idx - WP_V;   logN = 8; }
  else if (idx < WP_OFF) { src = wo;    r = idx - WP_O;   logN = 8; }
  else if (idx < WP_ATT) { src = w_off; r = idx - WP_OFF; logN = 8; }
  else if (idx < WP_OUT) { src = w_att; r = idx - WP_ATT; logN = 7; }
  else if (idx < WP_W1)  { src = w_out; r = idx - WP_OUT; logN = 8; }
  else if (idx < WP_W2)  { src = w1;    r = idx - WP_W1;  logN = 10; }
  else                   { src = w2;    r = idx - WP_W2;  logN = 8; }
  const int N = 1 << logN;
  const int e = r & 7, cs = (r >> 3) & 3;
  const int n = (r >> 5) & (N - 1);
  const int kt = r >> (5 + logN);
  const int c = cs ^ ((n >> 1) & 3);
  const int k = kt * 32 + c * 8 + e;
  Wp[idx] = f2bf(src[(size_t)k * N + n]);
}

// ---------------- value GEMM v5: barrier-free, LDS-free K-loop, direct-global A and B ----------------
// Block 64 rows x 128 cols; wave (wr,wc) owns rows wr*32..+31, cols wc*64..+63.
__global__ __launch_bounds__(256) void value_gemm5(const float* __restrict__ A,
                                                   const unsigned short* __restrict__ Wp,
                                                   const float* __restrict__ bias,
                                                   unsigned short* __restrict__ C,
                                                   int M) {
  __shared__ short strips[4 * 2176];   // epilogue only: per-wave 32 x 68 shorts
  const int tid = threadIdx.x;
  const int lane = tid & 63, w = tid >> 6;
  const int wr = w >> 1, wc = w & 1;
  const int l15 = lane & 15, lc = lane >> 4;
  const int nwg = gridDim.x;
  const int qq = nwg >> 3, rr = nwg & 7;
  const int xcd = blockIdx.x & 7, pos = blockIdx.x >> 3;
  const int wgid = (xcd < rr ? xcd * (qq + 1) : rr * (qq + 1) + (xcd - rr) * qq) + pos;
  const int m0 = (wgid >> 1) * 64, n0 = (wgid & 1) * 128;
  // per-lane A rows for the two frags (clamped)
  const int row0 = min(m0 + wr * 32 + l15, M - 1);
  const int row1 = min(m0 + wr * 32 + 16 + l15, M - 1);
  const float* a0p = A + (size_t)row0 * 256 + lc * 8;
  const float* a1p = A + (size_t)row1 * 256 + lc * 8;
  f32x4 acc[2][4] = {};
#pragma unroll
  for (int kt = 0; kt < 8; kt++) {
    bf16x8 af[2];
    {
      const float4 x0 = ((const float4*)(a0p + kt * 32))[0];
      const float4 x1 = ((const float4*)(a0p + kt * 32))[1];
      af[0][0] = (short)f2bf(x0.x); af[0][1] = (short)f2bf(x0.y);
      af[0][2] = (short)f2bf(x0.z); af[0][3] = (short)f2bf(x0.w);
      af[0][4] = (short)f2bf(x1.x); af[0][5] = (short)f2bf(x1.y);
      af[0][6] = (short)f2bf(x1.z); af[0][7] = (short)f2bf(x1.w);
      const float4 y0 = ((const float4*)(a1p + kt * 32))[0];
      const float4 y1 = ((const float4*)(a1p + kt * 32))[1];
      af[1][0] = (short)f2bf(y0.x); af[1][1] = (short)f2bf(y0.y);
      af[1][2] = (short)f2bf(y0.z); af[1][3] = (short)f2bf(y0.w);
      af[1][4] = (short)f2bf(y1.x); af[1][5] = (short)f2bf(y1.y);
      af[1][6] = (short)f2bf(y1.z); af[1][7] = (short)f2bf(y1.w);
    }
    bf16x8 bq[4];
#pragma unroll
    for (int q = 0; q < 4; q++) {
      const int col = n0 + wc * 64 + q * 16 + l15;
      bq[q] = *(const bf16x8*)(Wp + ((size_t)(kt * 256 + col)) * 32 +
                               ((lc ^ ((col >> 1) & 3)) << 3));
    }
#pragma unroll
    for (int i = 0; i < 2; i++)
#pragma unroll
      for (int q = 0; q < 4; q++)
        acc[i][q] = __builtin_amdgcn_mfma_f32_16x16x32_bf16(af[i], bq[q], acc[i][q], 0, 0, 0);
  }
  // ---- epilogue: bias + bf16 via per-wave strip, coalesced 16B stores ----
  short* strip = strips + w * 2176;
  float bv[4];
#pragma unroll
  for (int q = 0; q < 4; q++) bv[q] = bias[n0 + wc * 64 + q * 16 + l15];
#pragma unroll
  for (int i = 0; i < 2; i++)
#pragma unroll
    for (int q = 0; q < 4; q++)
#pragma unroll
      for (int r = 0; r < 4; r++)
        strip[(i * 16 + lc * 4 + r) * 68 + q * 16 + l15] = (short)f2bf(acc[i][q][r] + bv[q]);
  __builtin_amdgcn_s_barrier();   // wave-local ordering is enough, but barrier is cheap here (once)
#pragma unroll
  for (int p = 0; p < 4; p++) {
    const int row = p * 8 + (lane >> 3), c8 = lane & 7;
    const bf16x8 v = *(const bf16x8*)&strip[row * 68 + c8 * 8];
    const int grow = m0 + wr * 32 + row;
    if (grow < M)
      *(bf16x8*)(C + (size_t)grow * 256 + n0 + wc * 64 + c8 * 8) = v;
  }
}

// ---------------- shared GEMM body: 64x64 tile, packed B, pipelined (1 barrier/iter) ----------------
__device__ __forceinline__ void gemm_body(const void* Aptr, const float* A2,
                                          const unsigned short* __restrict__ Wp,
                                          const float* __restrict__ bias, void* Cptr,
                                          int M, int Nn, int K, float scale, int relu,
                                          int a_bf16, int out_bf16, int m0, int n0,
                                          short* As, short* Bs) {
  const int tid = threadIdx.x;
  const int lane = tid & 63, w = tid >> 6;
  const int wr = w >> 1, wc = w & 1;
  const int ar = tid >> 2, ac = tid & 3;
  const int l15 = lane & 15, lc = lane >> 4;
  const int arow = min(m0 + ar, M - 1);
  f32x4 acc[2][2] = {};
  float4 pa0, pa1, pc0, pc1; bf16x8 pav; uint4 pb;
  {
    if (a_bf16) {
      pav = *(const bf16x8*)((const unsigned short*)Aptr + (size_t)arow * K + ac * 8);
    } else {
      const float* ap_ = (const float*)Aptr + (size_t)arow * K + ac * 8;
      pa0 = ((const float4*)ap_)[0]; pa1 = ((const float4*)ap_)[1];
      if (A2) {
        const float* cp_ = A2 + (size_t)arow * K + ac * 8;
        pc0 = ((const float4*)cp_)[0]; pc1 = ((const float4*)cp_)[1];
      }
    }
    pb = *(const uint4*)(Wp + ((size_t)n0) * 32 + tid * 8);
  }
  for (int kt = 0; kt < K; kt += 32) {
    short* Ac = As + ((kt >> 5) & 1) * 2048;
    short* Bc = Bs + ((kt >> 5) & 1) * 2048;
    {
      bf16x8 av;
      if (a_bf16) {
        av = pav;
      } else {
        float4 a0 = pa0, a1 = pa1;
        if (A2) {
          a0.x += pc0.x; a0.y += pc0.y; a0.z += pc0.z; a0.w += pc0.w;
          a1.x += pc1.x; a1.y += pc1.y; a1.z += pc1.z; a1.w += pc1.w;
        }
        av[0] = (short)f2bf(a0.x); av[1] = (short)f2bf(a0.y);
        av[2] = (short)f2bf(a0.z); av[3] = (short)f2bf(a0.w);
        av[4] = (short)f2bf(a1.x); av[5] = (short)f2bf(a1.y);
        av[6] = (short)f2bf(a1.z); av[7] = (short)f2bf(a1.w);
      }
      *(bf16x8*)&Ac[ar * 32 + ((ac ^ ((ar >> 1) & 3)) << 3)] = av;
      *(uint4*)&Bc[tid * 8] = pb;
    }
    __syncthreads();
    if (kt + 32 < K) {   // prefetch next tile into regs
      if (a_bf16) {
        pav = *(const bf16x8*)((const unsigned short*)Aptr + (size_t)arow * K + kt + 32 + ac * 8);
      } else {
        const float* ap_ = (const float*)Aptr + (size_t)arow * K + kt + 32 + ac * 8;
        pa0 = ((const float4*)ap_)[0]; pa1 = ((const float4*)ap_)[1];
        if (A2) {
          const float* cp_ = A2 + (size_t)arow * K + kt + 32 + ac * 8;
          pc0 = ((const float4*)cp_)[0]; pc1 = ((const float4*)cp_)[1];
        }
      }
      pb = *(const uint4*)(Wp + ((size_t)(((kt >> 5) + 1) * Nn + n0)) * 32 + tid * 8);
    }
    bf16x8 af[2], bf[2];
#pragma unroll
    for (int i = 0; i < 2; i++) {
      const int row = wr * 32 + i * 16 + l15;
      af[i] = *(const bf16x8*)&Ac[row * 32 + ((lc ^ ((row >> 1) & 3)) << 3)];
      const int col = wc * 32 + i * 16 + l15;
      bf[i] = *(const bf16x8*)&Bc[col * 32 + ((lc ^ ((col >> 1) & 3)) << 3)];
    }
#pragma unroll
    for (int i = 0; i < 2; i++)
#pragma unroll
      for (int j = 0; j < 2; j++)
        acc[i][j] = __builtin_amdgcn_mfma_f32_16x16x32_bf16(af[i], bf[j], acc[i][j], 0, 0, 0);
  }
#pragma unroll
  for (int i = 0; i < 2; i++) {
    const int row0 = m0 + wr * 32 + i * 16 + lc * 4;
#pragma unroll
    for (int j = 0; j < 2; j++) {
      const int col = n0 + wc * 32 + j * 16 + l15;
      const float bv = bias[col];
#pragma unroll
      for (int r = 0; r < 4; r++) {
        const int row = row0 + r;
        if (row < M) {
          float v = (acc[i][j][r] + bv) * scale;
          if (relu) v = fmaxf(v, 0.f);
          if (out_bf16)
            ((unsigned short*)Cptr)[(size_t)row * Nn + col] = f2bf(v);
          else
            ((float*)Cptr)[(size_t)row * Nn + col] = v;
        }
      }
    }
  }
}

// ---------------- fused QKV projection: z selects Q/K/V; add(tgt,qpos) fused; bf16 out ----------------
__global__ __launch_bounds__(256) void gemm_qkv(const float* __restrict__ tgt,
                                                const float* __restrict__ qpos,
                                                const unsigned short* __restrict__ Wp,
                                                const float* __restrict__ bq_,
                                                const float* __restrict__ bk_,
                                                const float* __restrict__ bv_,
                                                unsigned short* Qb, unsigned short* Kb,
                                                unsigned short* Vb, float qscale) {
  __shared__ short As[2 * 2048];
  __shared__ short Bs[2 * 2048];
  const int z = blockIdx.z;
  const unsigned short* W = Wp + (z == 0 ? WP_Q : z == 1 ? WP_K : WP_V);
  const float* bias = (z == 0) ? bq_ : (z == 1) ? bk_ : bv_;
  unsigned short* C = (z == 0) ? Qb : (z == 1) ? Kb : Vb;
  const float* A2 = (z == 2) ? nullptr : qpos;
  gemm_body(tgt, A2, W, bias, C, MROW, DM, DM, (z == 0) ? qscale : 1.f, 0, 0, 1,
            blockIdx.y * 64, blockIdx.x * 64, As, Bs);
}

// ---------------- fused offset+attention-logit projection: add(x1,qpos) fused ----------------
__global__ __launch_bounds__(256) void gemm_offatt(const float* __restrict__ x1,
                                                   const float* __restrict__ qpos,
                                                   const unsigned short* __restrict__ Wp,
                                                   const float* __restrict__ b_off,
                                                   const float* __restrict__ b_att,
                                                   float* offb, float* attb) {
  const int z = blockIdx.z;
  if (z == 1 && blockIdx.x >= 2) return;
  __shared__ short As[2 * 2048];
  __shared__ short Bs[2 * 2048];
  const unsigned short* W = Wp + (z ? WP_ATT : WP_OFF);
  const float* bias = z ? b_att : b_off;
  float* C = z ? attb : offb;
  const int Nn = z ? 128 : 256;
  gemm_body(x1, qpos, W, bias, C, MROW, Nn, DM, 1.f, 0, 0, 0,
            blockIdx.y * 64, blockIdx.x * 64, As, Bs);
}

// ---------------- generic GEMM dispatch (packed B) ----------------
__global__ __launch_bounds__(256) void gemm_fused(const void* A, const unsigned short* Wp,
                                                  const float* bias, void* C, int M, int Nn,
                                                  int K, float scale, int relu, int a_bf16,
                                                  int out_bf16) {
  __shared__ short As[2 * 2048];
  __shared__ short Bs[2 * 2048];
  gemm_body(A, nullptr, Wp, bias, C, M, Nn, K, scale, relu, a_bf16, out_bf16,
            blockIdx.y * 64, blockIdx.x * 64, As, Bs);
}

// ---------------- MFMA flash attention (bf16 in/out, next-tile reg prefetch) ----------------
__global__ __launch_bounds__(256) void attn_mfma(const unsigned short* __restrict__ Qg,
                                                 const unsigned short* __restrict__ Kg,
                                                 const unsigned short* __restrict__ Vg,
                                                 unsigned short* __restrict__ O) {
  __shared__ short Ks[2048];
  __shared__ short Vt[2048];
  __shared__ short Pl[4096];
  const int tid = threadIdx.x;
  const int lane = tid & 63, w = tid >> 6;
  const int l15 = lane & 15, lc = lane >> 4;
  const int h = blockIdx.y, b = blockIdx.z;
  const int q0 = blockIdx.x * 64;
  char* KsB = (char*)Ks; char* VtB = (char*)Vt; char* PlB = (char*)Pl + w * 2048;

  bf16x8 qa;
  {
    const int qrow = min(q0 + w * 16 + l15, LQ - 1);
    qa = *(const bf16x8*)(Qg + ((size_t)(b * LQ + qrow)) * DM + h * DH + lc * 8);
  }
  f32x4 o0 = {0.f, 0.f, 0.f, 0.f}, o1 = {0.f, 0.f, 0.f, 0.f};
  float mrow[4], lrow[4];
#pragma unroll
  for (int r = 0; r < 4; r++) { mrow[r] = -1e30f; lrow[r] = 0.f; }
  const int skey = tid >> 2, sq = tid & 3;

  // preload tile 0
  bf16x8 kb, vv;
  {
    const int kr = min(skey, LQ - 1);
    kb = *(const bf16x8*)(Kg + ((size_t)(b * LQ + kr)) * DM + h * DH + sq * 8);
    vv = *(const bf16x8*)(Vg + ((size_t)(b * LQ + kr)) * DM + h * DH + sq * 8);
  }
  for (int kt = 0; kt < LQ; kt += 64) {
    __syncthreads();   // prev tile's LDS reads done
    {
      *(bf16x8*)(KsB + ((skey * 64 + sq * 16) ^ ((skey & 7) << 4))) = kb;
#pragma unroll
      for (int j = 0; j < 8; j++) {
        const int dh = sq * 8 + j;
        const int qz = ((dh & 7) ^ (((dh >> 3) & 3) << 1)) << 4;
        *(short*)(VtB + ((dh * 128 + skey * 2) ^ qz)) = (short)vv[j];
      }
    }
    __syncthreads();   // staging visible
    if (kt + 64 < LQ) {   // prefetch next K/V tile; hides under S/softmax/PV below
      const int kr = min(kt + 64 + skey, LQ - 1);
      kb = *(const bf16x8*)(Kg + ((size_t)(b * LQ + kr)) * DM + h * DH + sq * 8);
      vv = *(const bf16x8*)(Vg + ((size_t)(b * LQ + kr)) * DM + h * DH + sq * 8);
    }
    f32x4 s[4];
#pragma unroll
    for (int cb = 0; cb < 4; cb++) {
      const int key = cb * 16 + l15;
      const bf16x8 kf = *(const bf16x8*)(KsB + ((key * 64 + lc * 16) ^ ((key & 7) << 4)));
      const f32x4 z = {0.f, 0.f, 0.f, 0.f};
      s[cb] = __builtin_amdgcn_mfma_f32_16x16x32_bf16(qa, kf, z, 0, 0, 0);
    }
#pragma unroll
    for (int cb = 0; cb < 4; cb++)
      if (kt + cb * 16 + l15 >= LQ) {
        s[cb][0] = -1e30f; s[cb][1] = -1e30f; s[cb][2] = -1e30f; s[cb][3] = -1e30f;
      }
    float tm[4], fs[4], ps[4];
#pragma unroll
    for (int r = 0; r < 4; r++)
      tm[r] = fmaxf(fmaxf(s[0][r], s[1][r]), fmaxf(s[2][r], s[3][r]));
#pragma unroll
    for (int msk = 1; msk <= 8; msk <<= 1)
#pragma unroll
      for (int r = 0; r < 4; r++) tm[r] = fmaxf(tm[r], __shfl_xor(tm[r], msk));
#pragma unroll
    for (int r = 0; r < 4; r++) {
      const float nm = fmaxf(mrow[r], tm[r]);
      fs[r] = __expf(mrow[r] - nm);
      mrow[r] = nm;
    }
#pragma unroll
    for (int cb = 0; cb < 4; cb++)
#pragma unroll
      for (int r = 0; r < 4; r++) s[cb][r] = __expf(s[cb][r] - mrow[r]);
#pragma unroll
    for (int r = 0; r < 4; r++) ps[r] = (s[0][r] + s[1][r]) + (s[2][r] + s[3][r]);
#pragma unroll
    for (int msk = 1; msk <= 8; msk <<= 1)
#pragma unroll
      for (int r = 0; r < 4; r++) ps[r] += __shfl_xor(ps[r], msk);
#pragma unroll
    for (int r = 0; r < 4; r++) {
      lrow[r] = lrow[r] * fs[r] + ps[r];
      o0[r] *= fs[r]; o1[r] *= fs[r];
    }
#pragma unroll
    for (int cb = 0; cb < 4; cb++)
#pragma unroll
      for (int r = 0; r < 4; r++) {
        const int row = lc * 4 + r, col = cb * 16 + l15;
        *(short*)(PlB + ((row * 128 + col * 2) ^ ((row & 7) << 4))) = (short)f2bf(s[cb][r]);
      }
#pragma unroll
    for (int ks2 = 0; ks2 < 2; ks2++) {
      const int koff2 = (ks2 * 32 + lc * 8) * 2;
      const bf16x8 pa = *(const bf16x8*)(PlB + ((l15 * 128 + koff2) ^ ((l15 & 7) << 4)));
      {
        const int dh = l15;
        const int qz = ((dh & 7) ^ (((dh >> 3) & 3) << 1)) << 4;
        const bf16x8 vf = *(const bf16x8*)(VtB + ((dh * 128 + koff2) ^ qz));
        o0 = __builtin_amdgcn_mfma_f32_16x16x32_bf16(pa, vf, o0, 0, 0, 0);
      }
      {
        const int dh = 16 + l15;
        const int qz = ((dh & 7) ^ (((dh >> 3) & 3) << 1)) << 4;
        const bf16x8 vf = *(const bf16x8*)(VtB + ((dh * 128 + koff2) ^ qz));
        o1 = __builtin_amdgcn_mfma_f32_16x16x32_bf16(pa, vf, o1, 0, 0, 0);
      }
    }
  }
#pragma unroll
  for (int r = 0; r < 4; r++) {
    const int qrow = q0 + w * 16 + lc * 4 + r;
    if (qrow < LQ) {
      const float inv = 1.f / lrow[r];
      unsigned short* op = O + ((size_t)(b * LQ + qrow)) * DM + h * DH;
      op[l15] = f2bf(o0[r] * inv);
      op[16 + l15] = f2bf(o1[r] * inv);
    }
  }
}

// ---------------- MS-deform sampling: 8 threads per (b,q,h), 4 channels each; bf16 out ----------------
__global__ __launch_bounds__(256) void sample_kernel(const unsigned short* __restrict__ value,
                                                     const float* __restrict__ ref,
                                                     const float* __restrict__ off,
                                                     const float* __restrict__ att,
                                                     unsigned short* __restrict__ out) {
  const int t = blockIdx.x * 256 + threadIdx.x;   // < NB*LQ*NH*8 = 460800
  const int d4 = t & 7;
  const int h = (t >> 3) & 7;
  const int qb = t >> 6;                           // b*LQ + q
  const int b = qb / LQ;
  const int HLs[4] = {100, 50, 25, 13};
  const int STs[4] = {0, 10000, 12500, 13125};
  const float* rp = ref + (size_t)qb * (NL * 2);
  const float* op = off + (size_t)qb * DM + h * (NL * NP * 2);
  const float* ap = att + (size_t)qb * (NH * NL * NP) + h * (NL * NP);
  const unsigned short* vb = value + (size_t)b * LIN * DM + h * DH + d4 * 4;

  float aw[16];
#pragma unroll
  for (int i = 0; i < 4; i++) {
    const float4 a4 = ((const float4*)ap)[i];
    aw[4 * i] = a4.x; aw[4 * i + 1] = a4.y; aw[4 * i + 2] = a4.z; aw[4 * i + 3] = a4.w;
  }
  float am = aw[0];
#pragma unroll
  for (int i = 1; i < 16; i++) am = fmaxf(am, aw[i]);
  float asum = 0.f;
#pragma unroll
  for (int i = 0; i < 16; i++) { aw[i] = __expf(aw[i] - am); asum += aw[i]; }
  const float ainv = 1.f / asum;

  float acc[4] = {};
#pragma unroll
  for (int l = 0; l < NL; l++) {
    const int Hl = HLs[l], Wl = HLs[l], st = STs[l];
    const float rx = rp[l * 2], ry = rp[l * 2 + 1];
#pragma unroll
    for (int p = 0; p < NP; p++) {
      const float2 o2 = ((const float2*)op)[l * NP + p];
      const float a = aw[l * NP + p] * ainv;
      const float locx = rx + o2.x / (float)Wl;
      const float locy = ry + o2.y / (float)Hl;
      const float x = locx * (float)Wl - 0.5f;
      const float y = locy * (float)Hl - 0.5f;
      const float xf = floorf(x), yf = floorf(y);
      const float fx = x - xf, fy = y - yf;
      const int x0 = (int)xf, y0 = (int)yf;
      const int x1 = x0 + 1, y1 = y0 + 1;
      const float vx0 = (x0 >= 0 && x0 < Wl) ? 1.f : 0.f;
      const float vx1 = (x1 >= 0 && x1 < Wl) ? 1.f : 0.f;
      const float vy0 = (y0 >= 0 && y0 < Hl) ? 1.f : 0.f;
      const float vy1 = (y1 >= 0 && y1 < Hl) ? 1.f : 0.f;
      const int cx0 = min(max(x0, 0), Wl - 1), cx1 = min(max(x1, 0), Wl - 1);
      const int cy0 = min(max(y0, 0), Hl - 1), cy1 = min(max(y1, 0), Hl - 1);
      const float w00 = a * (1.f - fx) * (1.f - fy) * vx0 * vy0;
      const float w10 = a * fx * (1.f - fy) * vx1 * vy0;
      const float w01 = a * (1.f - fx) * fy * vx0 * vy1;
      const float w11 = a * fx * fy * vx1 * vy1;
      const unsigned short* r0 = vb + (size_t)(st + cy0 * Wl) * DM;
      const unsigned short* r1 = vb + (size_t)(st + cy1 * Wl) * DM;
      const uint2 g00 = *(const uint2*)(r0 + (size_t)cx0 * DM);
      const uint2 g10 = *(const uint2*)(r0 + (size_t)cx1 * DM);
      const uint2 g01 = *(const uint2*)(r1 + (size_t)cx0 * DM);
      const uint2 g11 = *(const uint2*)(r1 + (size_t)cx1 * DM);
      const unsigned u00[2] = {g00.x, g00.y};
      const unsigned u10[2] = {g10.x, g10.y};
      const unsigned u01[2] = {g01.x, g01.y};
      const unsigned u11[2] = {g11.x, g11.y};
#pragma unroll
      for (int i = 0; i < 2; i++) {
        acc[2 * i]     += w00 * __uint_as_float(u00[i] << 16) + w10 * __uint_as_float(u10[i] << 16)
                        + w01 * __uint_as_float(u01[i] << 16) + w11 * __uint_as_float(u11[i] << 16);
        acc[2 * i + 1] += w00 * __uint_as_float(u00[i] & 0xFFFF0000u) + w10 * __uint_as_float(u10[i] & 0xFFFF0000u)
                        + w01 * __uint_as_float(u01[i] & 0xFFFF0000u) + w11 * __uint_as_float(u11[i] & 0xFFFF0000u);
      }
    }
  }
  uint2 ov;
  ov.x = (unsigned)f2bf(acc[0]) | ((unsigned)f2bf(acc[1]) << 16);
  ov.y = (unsigned)f2bf(acc[2]) | ((unsigned)f2bf(acc[3]) << 16);
  *(uint2*)(out + (size_t)t * 4) = ov;
}

// ---------------- fused residual-add + LayerNorm, 4 rows per block (1 wave/row) ----------------
__global__ __launch_bounds__(256) void ln_kernel(const float* __restrict__ A,
                                                 const float* __restrict__ R,
                                                 const float* __restrict__ g,
                                                 const float* __restrict__ be,
                                                 float* __restrict__ out) {
  const int row = blockIdx.x * 4 + (threadIdx.x >> 6);
  const int t = threadIdx.x & 63;
  const float4 va = ((const float4*)(A + (size_t)row * DM))[t];
  const float4 vr = ((const float4*)(R + (size_t)row * DM))[t];
  const float x0 = va.x + vr.x, x1 = va.y + vr.y, x2 = va.z + vr.z, x3 = va.w + vr.w;
  float s = x0 + x1 + x2 + x3;
  float ss = x0 * x0 + x1 * x1 + x2 * x2 + x3 * x3;
#pragma unroll
  for (int o = 1; o < 64; o <<= 1) { s += __shfl_xor(s, o); ss += __shfl_xor(ss, o); }
  const float mean = s * (1.f / DM);
  const float var = ss * (1.f / DM) - mean * mean;
  const float rstd = rsqrtf(var + 1e-5f);
  const float4 vg = ((const float4*)g)[t];
  const float4 vb = ((const float4*)be)[t];
  float4 o4;
  o4.x = (x0 - mean) * rstd * vg.x + vb.x;
  o4.y = (x1 - mean) * rstd * vg.y + vb.y;
  o4.z = (x2 - mean) * rstd * vg.z + vb.z;
  o4.w = (x3 - mean) * rstd * vg.w + vb.w;
  ((float4*)(out + (size_t)row * DM))[t] = o4;
}

extern "C" void kernel_launch(void* const* d_in, const int* in_sizes, int n_in,
                              void* d_out, int out_size, void* d_ws, size_t ws_size,
                              hipStream_t stream) {
  const float* tgt  = (const float*)d_in[1];
  const float* qpos = (const float*)d_in[2];
  const float* ref  = (const float*)d_in[3];
  const float* src  = (const float*)d_in[4];
  const float* wq = (const float*)d_in[8];  const float* bq = (const float*)d_in[9];
  const float* wk = (const float*)d_in[10]; const float* bk = (const float*)d_in[11];
  const float* wv = (const float*)d_in[12]; const float* bv = (const float*)d_in[13];
  const float* wo = (const float*)d_in[14]; const float* bo = (const float*)d_in[15];
  const float* w_val = (const float*)d_in[16]; const float* b_val = (const float*)d_in[17];
  const float* w_off = (const float*)d_in[18]; const float* b_off = (const float*)d_in[19];
  const float* w_att = (const float*)d_in[20]; const float* b_att = (const float*)d_in[21];
  const float* w_out = (const float*)d_in[22]; const float* b_out = (const float*)d_in[23];
  const float* ln1g = (const float*)d_in[24]; const float* ln1b = (const float*)d_in[25];
  const float* ln2g = (const float*)d_in[26]; const float* ln2b = (const float*)d_in[27];
  const float* ln3g = (const float*)d_in[28]; const float* ln3b = (const float*)d_in[29];
  const float* w1 = (const float*)d_in[30]; const float* b1 = (const float*)d_in[31];
  const float* w2 = (const float*)d_in[32]; const float* b2 = (const float*)d_in[33];

  const size_t S = (size_t)MROW * DM;
  const size_t VAL_F = (size_t)NVAL * DM;
  float* ws = (float*)d_ws;
  float* value = ws;                 // bf16: floats [0, VAL_F/2)
  unsigned short* wp = (unsigned short*)(ws + VAL_F / 2);  // ~2 MB packed weights
  float* B0   = ws + VAL_F;
  unsigned short* Qb = (unsigned short*)(B0 + 1 * S);   // bf16
  unsigned short* Kb = (unsigned short*)(B0 + 2 * S);   // bf16
  unsigned short* Vb = (unsigned short*)(B0 + 3 * S);   // bf16
  unsigned short* Ob = (unsigned short*)(B0 + 4 * S);   // bf16
  float* tmp  = B0 + 5 * S;
  float* x1   = B0 + 0 * S;
  float* offb = B0 + 2 * S;
  float* attb = B0 + 3 * S;
  unsigned short* samp = (unsigned short*)(B0 + 4 * S); // bf16 (Ob dead by then)
  float* x2   = B0 + 6 * S;
  unsigned short* hffn = (unsigned short*)(B0 + 1 * S); // bf16, spans [1S,3S)

  const float qscale = 0.17677669529663687f;  // 1/sqrt(32)
  const dim3 blk(256);
  const dim3 gQ(DM / 64, (MROW + 63) / 64);            // (4,113)

  // ---- weight pack (one dispatch, all 10 matrices) ----
  pack_all<<<dim3(WP_TOT / 256), blk, 0, stream>>>(w_val, wq, wk, wv, wo, w_off, w_att,
                                                   w_out, w1, w2, wp);

  // ---- self-attention ----
  gemm_qkv<<<dim3(4, 113, 3), blk, 0, stream>>>(tgt, qpos, wp, bq, bk, bv,
                                                Qb, Kb, Vb, qscale);
  attn_mfma<<<dim3((LQ + 63) / 64, NH, NB), blk, 0, stream>>>(Qb, Kb, Vb, Ob);
  gemm_fused<<<gQ, blk, 0, stream>>>(Ob, wp + WP_O, bo, tmp, MROW, DM, DM, 1.f, 0, 1, 0);
  ln_kernel<<<dim3(MROW / 4), blk, 0, stream>>>(tmp, tgt, ln2g, ln2b, x1);

  // ---- deformable cross-attention ----
  value_gemm5<<<dim3(GVAL2), blk, 0, stream>>>(src, wp + WP_VAL, b_val,
                                               (unsigned short*)value, NVAL);
  gemm_offatt<<<dim3(4, 113, 2), blk, 0, stream>>>(x1, qpos, wp, b_off, b_att, offb, attb);
  sample_kernel<<<dim3((MROW * NH * 8) / 256), blk, 0, stream>>>(
      (const unsigned short*)value, ref, offb, attb, samp);
  gemm_fused<<<gQ, blk, 0, stream>>>(samp, wp + WP_OUT, b_out, tmp, MROW, DM, DM,
                                     1.f, 0, 1, 0);
  ln_kernel<<<dim3(MROW / 4), blk, 0, stream>>>(tmp, x1, ln1g, ln1b, x2);

  // ---- FFN ----
  gemm_fused<<<dim3(DFFN / 64, 113), blk, 0, stream>>>(x2, wp + WP_W1, b1, hffn, MROW,
                                                       DFFN, DM, 1.f, 1, 0, 1);
  gemm_fused<<<gQ, blk, 0, stream>>>(hffn, wp + WP_W2, b2, tmp, MROW, DM, DFFN,
                                     1.f, 0, 1, 0);
  ln_kernel<<<dim3(MROW / 4), blk, 0, stream>>>(tmp, x2, ln3g, ln3b, (float*)d_out);
}

// Round 14
// 234.666 us; speedup vs baseline: 1.1064x; 1.1064x over previous
//
#include <hip/hip_runtime.h>
#include <math.h>

#define NB 8
#define LQ 900
#define DM 256
#define NH 8
#define DH 32
#define NL 4
#define NP 4
#define DFFN 1024
#define LIN 13294
#define NVAL (NB*LIN)      // 106352 rows for value projection
#define MROW (NB*LQ)       // 7200 rows for query-side matmuls
#define GVAL2 3324         // 1662 M-strips(64) x 2 N-halves(128)

// packed-weight segment offsets (shorts)
#define WP_VAL 0
#define WP_Q   65536
#define WP_K   131072
#define WP_V   196608
#define WP_O   262144
#define WP_OFF 327680
#define WP_ATT 393216
#define WP_OUT 425984
#define WP_W1  491520
#define WP_W2  753664
#define WP_TOT 1015808     // = 3968 * 256

typedef __attribute__((ext_vector_type(8))) short bf16x8;
typedef __attribute__((ext_vector_type(4))) float f32x4;

__device__ __forceinline__ unsigned short f2bf(float x) {
  unsigned u = __float_as_uint(x);
  u += 0x7FFFu + ((u >> 16) & 1u);   // round-to-nearest-even
  return (unsigned short)(u >> 16);
}

// async global->LDS, 16B per lane; LDS dest = wave-uniform base + lane*16 (HW)
__device__ __forceinline__ void gload_lds16(const void* g, void* l) {
  __builtin_amdgcn_global_load_lds(
      (const __attribute__((address_space(1))) unsigned*)g,
      (__attribute__((address_space(3))) unsigned*)l, 16, 0, 0);
}

// ---------------- pack ALL weights: fp32 [k][n] -> bf16 tiled [kt][n][32], pre-swizzled ----------------
__global__ __launch_bounds__(256) void pack_all(
    const float* __restrict__ w_val, const float* __restrict__ wq,
    const float* __restrict__ wk, const float* __restrict__ wv,
    const float* __restrict__ wo, const float* __restrict__ w_off,
    const float* __restrict__ w_att, const float* __restrict__ w_out,
    const float* __restrict__ w1, const float* __restrict__ w2,
    unsigned short* __restrict__ Wp) {
  const int idx = blockIdx.x * 256 + threadIdx.x;
  const float* src; int r, logN;
  if (idx < WP_Q)        { src = w_val; r = idx;          logN = 8; }
  else if (idx < WP_K)   { src = wq;    r = idx - WP_Q;   logN = 8; }
  else if (idx < WP_V)   { src = wk;    r = idx - WP_K;   logN = 8; }
  else if (idx < WP_O)   { src = wv;    r = idx - WP_V;   logN = 8; }
  else if (idx < WP_OFF) { src = wo;    r = idx - WP_O;   logN = 8; }
  else if (idx < WP_ATT) { src = w_off; r = idx - WP_OFF; logN = 8; }
  else if (idx < WP_OUT) { src = w_att; r = idx - WP_ATT; logN = 7; }
  else if (idx < WP_W1)  { src = w_out; r = idx - WP_OUT; logN = 8; }
  else if (idx < WP_W2)  { src = w1;    r = idx - WP_W1;  logN = 10; }
  else                   { src = w2;    r = idx - WP_W2;  logN = 8; }
  const int N = 1 << logN;
  const int e = r & 7, cs = (r >> 3) & 3;
  const int n = (r >> 5) & (N - 1);
  const int kt = r >> (5 + logN);
  const int c = cs ^ ((n >> 1) & 3);
  const int k = kt * 32 + c * 8 + e;
  Wp[idx] = f2bf(src[(size_t)k * N + n]);
}

// ---------------- value GEMM v6: v4 structure + global_load_lds B staging ----------------
__global__ __launch_bounds__(256) void value_gemm6(const float* __restrict__ A,
                                                   const unsigned short* __restrict__ Wp,
                                                   const float* __restrict__ bias,
                                                   unsigned short* __restrict__ C,
                                                   int M) {
  __shared__ char lds[24576];
  short* As = (short*)lds;             // 2 x 2048 shorts (64x32, chunk-swizzled)
  short* Bs = (short*)(lds + 8192);    // 2 x 4096 shorts (128x32, linear pre-swizzled)
  const int tid = threadIdx.x;
  const int lane = tid & 63, w = tid >> 6;
  const int wr = w >> 1, wc = w & 1;
  const int l15 = lane & 15, lc = lane >> 4;
  const int nwg = gridDim.x;
  const int qq = nwg >> 3, rr = nwg & 7;
  const int xcd = blockIdx.x & 7, pos = blockIdx.x >> 3;
  const int wgid = (xcd < rr ? xcd * (qq + 1) : rr * (qq + 1) + (xcd - rr) * qq) + pos;
  const int m0 = (wgid >> 1) * 64, n0 = (wgid & 1) * 128;
  const int ar = tid >> 2, ac = tid & 3;
  const int arow = min(m0 + ar, M - 1);
  const char* WpB = (const char*)Wp;   // byte view of packed B
  f32x4 acc[2][4] = {};
  float4 pa0, pa1;
  {
    const float* ap_ = A + (size_t)arow * 256 + ac * 8;
    pa0 = ((const float4*)ap_)[0]; pa1 = ((const float4*)ap_)[1];
    // B DMA tile 0 -> buf0 (2KB per wave, two 1KB instructions)
    const char* wb = WpB + ((size_t)n0) * 64 + w * 2048 + lane * 16;
    gload_lds16(wb, (char*)Bs + w * 2048);
    gload_lds16(wb + 1024, (char*)Bs + w * 2048 + 1024);
  }
#pragma unroll
  for (int kt = 0; kt < 256; kt += 32) {
    const int cur = (kt >> 5) & 1;
    short* Ac = As + cur * 2048;
    short* Bc = Bs + cur * 4096;
    {
      bf16x8 av;
      av[0] = (short)f2bf(pa0.x); av[1] = (short)f2bf(pa0.y);
      av[2] = (short)f2bf(pa0.z); av[3] = (short)f2bf(pa0.w);
      av[4] = (short)f2bf(pa1.x); av[5] = (short)f2bf(pa1.y);
      av[6] = (short)f2bf(pa1.z); av[7] = (short)f2bf(pa1.w);
      *(bf16x8*)&Ac[ar * 32 + ((ac ^ ((ar >> 1) & 3)) << 3)] = av;
    }
    __syncthreads();   // drains this tile's B DMA; A staged; prev reads done
    if (kt + 32 < 256) {
      const float* ap_ = A + (size_t)arow * 256 + kt + 32 + ac * 8;
      pa0 = ((const float4*)ap_)[0]; pa1 = ((const float4*)ap_)[1];
      const char* wb = WpB + ((size_t)(((kt >> 5) + 1) * 256 + n0)) * 64 + w * 2048 + lane * 16;
      char* bdst = (char*)(Bs + (cur ^ 1) * 4096) + w * 2048;
      gload_lds16(wb, bdst);
      gload_lds16(wb + 1024, bdst + 1024);
    }
    bf16x8 af[2], bq[4];
#pragma unroll
    for (int i = 0; i < 2; i++) {
      const int row = wr * 32 + i * 16 + l15;
      af[i] = *(const bf16x8*)&Ac[row * 32 + ((lc ^ ((row >> 1) & 3)) << 3)];
    }
#pragma unroll
    for (int q = 0; q < 4; q++) {
      const int col = wc * 64 + q * 16 + l15;
      bq[q] = *(const bf16x8*)&Bc[col * 32 + ((lc ^ ((col >> 1) & 3)) << 3)];
    }
#pragma unroll
    for (int i = 0; i < 2; i++)
#pragma unroll
      for (int q = 0; q < 4; q++)
        acc[i][q] = __builtin_amdgcn_mfma_f32_16x16x32_bf16(af[i], bq[q], acc[i][q], 0, 0, 0);
  }
  // ---- epilogue: bias + bf16 via per-wave strip, coalesced 16B stores ----
  __syncthreads();
  short* strip = (short*)lds + w * 2176;   // 32 rows x 68 shorts
  float bv[4];
#pragma unroll
  for (int q = 0; q < 4; q++) bv[q] = bias[n0 + wc * 64 + q * 16 + l15];
#pragma unroll
  for (int i = 0; i < 2; i++)
#pragma unroll
    for (int q = 0; q < 4; q++)
#pragma unroll
      for (int r = 0; r < 4; r++)
        strip[(i * 16 + lc * 4 + r) * 68 + q * 16 + l15] = (short)f2bf(acc[i][q][r] + bv[q]);
  __syncthreads();
#pragma unroll
  for (int p = 0; p < 4; p++) {
    const int row = p * 8 + (lane >> 3), c8 = lane & 7;
    const bf16x8 v = *(const bf16x8*)&strip[row * 68 + c8 * 8];
    const int grow = m0 + wr * 32 + row;
    if (grow < M)
      *(bf16x8*)(C + (size_t)grow * 256 + n0 + wc * 64 + c8 * 8) = v;
  }
}

// ---------------- shared GEMM body: 64x64 tile, packed B via global_load_lds, pipelined ----------------
__device__ __forceinline__ void gemm_body(const void* Aptr, const float* A2,
                                          const unsigned short* __restrict__ Wp,
                                          const float* __restrict__ bias, void* Cptr,
                                          int M, int Nn, int K, float scale, int relu,
                                          int a_bf16, int out_bf16, int m0, int n0,
                                          short* As, short* Bs) {
  const int tid = threadIdx.x;
  const int lane = tid & 63, w = tid >> 6;
  const int wr = w >> 1, wc = w & 1;
  const int ar = tid >> 2, ac = tid & 3;
  const int l15 = lane & 15, lc = lane >> 4;
  const int arow = min(m0 + ar, M - 1);
  const char* WpB = (const char*)Wp;
  f32x4 acc[2][2] = {};
  float4 pa0, pa1, pc0, pc1; bf16x8 pav;
  {
    if (a_bf16) {
      pav = *(const bf16x8*)((const unsigned short*)Aptr + (size_t)arow * K + ac * 8);
    } else {
      const float* ap_ = (const float*)Aptr + (size_t)arow * K + ac * 8;
      pa0 = ((const float4*)ap_)[0]; pa1 = ((const float4*)ap_)[1];
      if (A2) {
        const float* cp_ = A2 + (size_t)arow * K + ac * 8;
        pc0 = ((const float4*)cp_)[0]; pc1 = ((const float4*)cp_)[1];
      }
    }
    // B DMA tile 0 -> buf0 (1KB per wave)
    gload_lds16(WpB + ((size_t)n0) * 64 + w * 1024 + lane * 16, (char*)Bs + w * 1024);
  }
  for (int kt = 0; kt < K; kt += 32) {
    const int cur = (kt >> 5) & 1;
    short* Ac = As + cur * 2048;
    short* Bc = Bs + cur * 2048;
    {
      bf16x8 av;
      if (a_bf16) {
        av = pav;
      } else {
        float4 a0 = pa0, a1 = pa1;
        if (A2) {
          a0.x += pc0.x; a0.y += pc0.y; a0.z += pc0.z; a0.w += pc0.w;
          a1.x += pc1.x; a1.y += pc1.y; a1.z += pc1.z; a1.w += pc1.w;
        }
        av[0] = (short)f2bf(a0.x); av[1] = (short)f2bf(a0.y);
        av[2] = (short)f2bf(a0.z); av[3] = (short)f2bf(a0.w);
        av[4] = (short)f2bf(a1.x); av[5] = (short)f2bf(a1.y);
        av[6] = (short)f2bf(a1.z); av[7] = (short)f2bf(a1.w);
      }
      *(bf16x8*)&Ac[ar * 32 + ((ac ^ ((ar >> 1) & 3)) << 3)] = av;
    }
    __syncthreads();   // drains this tile's B DMA
    if (kt + 32 < K) {
      if (a_bf16) {
        pav = *(const bf16x8*)((const unsigned short*)Aptr + (size_t)arow * K + kt + 32 + ac * 8);
      } else {
        const float* ap_ = (const float*)Aptr + (size_t)arow * K + kt + 32 + ac * 8;
        pa0 = ((const float4*)ap_)[0]; pa1 = ((const float4*)ap_)[1];
        if (A2) {
          const float* cp_ = A2 + (size_t)arow * K + kt + 32 + ac * 8;
          pc0 = ((const float4*)cp_)[0]; pc1 = ((const float4*)cp_)[1];
        }
      }
      gload_lds16(WpB + ((size_t)(((kt >> 5) + 1) * Nn + n0)) * 64 + w * 1024 + lane * 16,
                  (char*)(Bs + (cur ^ 1) * 2048) + w * 1024);
    }
    bf16x8 af[2], bf[2];
#pragma unroll
    for (int i = 0; i < 2; i++) {
      const int row = wr * 32 + i * 16 + l15;
      af[i] = *(const bf16x8*)&Ac[row * 32 + ((lc ^ ((row >> 1) & 3)) << 3)];
      const int col = wc * 32 + i * 16 + l15;
      bf[i] = *(const bf16x8*)&Bc[col * 32 + ((lc ^ ((col >> 1) & 3)) << 3)];
    }
#pragma unroll
    for (int i = 0; i < 2; i++)
#pragma unroll
      for (int j = 0; j < 2; j++)
        acc[i][j] = __builtin_amdgcn_mfma_f32_16x16x32_bf16(af[i], bf[j], acc[i][j], 0, 0, 0);
  }
#pragma unroll
  for (int i = 0; i < 2; i++) {
    const int row0 = m0 + wr * 32 + i * 16 + lc * 4;
#pragma unroll
    for (int j = 0; j < 2; j++) {
      const int col = n0 + wc * 32 + j * 16 + l15;
      const float bv = bias[col];
#pragma unroll
      for (int r = 0; r < 4; r++) {
        const int row = row0 + r;
        if (row < M) {
          float v = (acc[i][j][r] + bv) * scale;
          if (relu) v = fmaxf(v, 0.f);
          if (out_bf16)
            ((unsigned short*)Cptr)[(size_t)row * Nn + col] = f2bf(v);
          else
            ((float*)Cptr)[(size_t)row * Nn + col] = v;
        }
      }
    }
  }
}

// ---------------- fused QKV projection: z selects Q/K/V; add(tgt,qpos) fused; bf16 out ----------------
__global__ __launch_bounds__(256) void gemm_qkv(const float* __restrict__ tgt,
                                                const float* __restrict__ qpos,
                                                const unsigned short* __restrict__ Wp,
                                                const float* __restrict__ bq_,
                                                const float* __restrict__ bk_,
                                                const float* __restrict__ bv_,
                                                unsigned short* Qb, unsigned short* Kb,
                                                unsigned short* Vb, float qscale) {
  __shared__ short As[2 * 2048];
  __shared__ short Bs[2 * 2048];
  const int z = blockIdx.z;
  const unsigned short* W = Wp + (z == 0 ? WP_Q : z == 1 ? WP_K : WP_V);
  const float* bias = (z == 0) ? bq_ : (z == 1) ? bk_ : bv_;
  unsigned short* C = (z == 0) ? Qb : (z == 1) ? Kb : Vb;
  const float* A2 = (z == 2) ? nullptr : qpos;
  gemm_body(tgt, A2, W, bias, C, MROW, DM, DM, (z == 0) ? qscale : 1.f, 0, 0, 1,
            blockIdx.y * 64, blockIdx.x * 64, As, Bs);
}

// ---------------- fused offset+attention-logit projection: add(x1,qpos) fused ----------------
__global__ __launch_bounds__(256) void gemm_offatt(const float* __restrict__ x1,
                                                   const float* __restrict__ qpos,
                                                   const unsigned short* __restrict__ Wp,
                                                   const float* __restrict__ b_off,
                                                   const float* __restrict__ b_att,
                                                   float* offb, float* attb) {
  const int z = blockIdx.z;
  if (z == 1 && blockIdx.x >= 2) return;
  __shared__ short As[2 * 2048];
  __shared__ short Bs[2 * 2048];
  const unsigned short* W = Wp + (z ? WP_ATT : WP_OFF);
  const float* bias = z ? b_att : b_off;
  float* C = z ? attb : offb;
  const int Nn = z ? 128 : 256;
  gemm_body(x1, qpos, W, bias, C, MROW, Nn, DM, 1.f, 0, 0, 0,
            blockIdx.y * 64, blockIdx.x * 64, As, Bs);
}

// ---------------- generic GEMM dispatch (packed B) ----------------
__global__ __launch_bounds__(256) void gemm_fused(const void* A, const unsigned short* Wp,
                                                  const float* bias, void* C, int M, int Nn,
                                                  int K, float scale, int relu, int a_bf16,
                                                  int out_bf16) {
  __shared__ short As[2 * 2048];
  __shared__ short Bs[2 * 2048];
  gemm_body(A, nullptr, Wp, bias, C, M, Nn, K, scale, relu, a_bf16, out_bf16,
            blockIdx.y * 64, blockIdx.x * 64, As, Bs);
}

// ---------------- MFMA flash attention (bf16 in/out, next-tile reg prefetch) ----------------
__global__ __launch_bounds__(256) void attn_mfma(const unsigned short* __restrict__ Qg,
                                                 const unsigned short* __restrict__ Kg,
                                                 const unsigned short* __restrict__ Vg,
                                                 unsigned short* __restrict__ O) {
  __shared__ short Ks[2048];
  __shared__ short Vt[2048];
  __shared__ short Pl[4096];
  const int tid = threadIdx.x;
  const int lane = tid & 63, w = tid >> 6;
  const int l15 = lane & 15, lc = lane >> 4;
  const int h = blockIdx.y, b = blockIdx.z;
  const int q0 = blockIdx.x * 64;
  char* KsB = (char*)Ks; char* VtB = (char*)Vt; char* PlB = (char*)Pl + w * 2048;

  bf16x8 qa;
  {
    const int qrow = min(q0 + w * 16 + l15, LQ - 1);
    qa = *(const bf16x8*)(Qg + ((size_t)(b * LQ + qrow)) * DM + h * DH + lc * 8);
  }
  f32x4 o0 = {0.f, 0.f, 0.f, 0.f}, o1 = {0.f, 0.f, 0.f, 0.f};
  float mrow[4], lrow[4];
#pragma unroll
  for (int r = 0; r < 4; r++) { mrow[r] = -1e30f; lrow[r] = 0.f; }
  const int skey = tid >> 2, sq = tid & 3;

  // preload tile 0
  bf16x8 kb, vv;
  {
    const int kr = min(skey, LQ - 1);
    kb = *(const bf16x8*)(Kg + ((size_t)(b * LQ + kr)) * DM + h * DH + sq * 8);
    vv = *(const bf16x8*)(Vg + ((size_t)(b * LQ + kr)) * DM + h * DH + sq * 8);
  }
  for (int kt = 0; kt < LQ; kt += 64) {
    __syncthreads();   // prev tile's LDS reads done
    {
      *(bf16x8*)(KsB + ((skey * 64 + sq * 16) ^ ((skey & 7) << 4))) = kb;
#pragma unroll
      for (int j = 0; j < 8; j++) {
        const int dh = sq * 8 + j;
        const int qz = ((dh & 7) ^ (((dh >> 3) & 3) << 1)) << 4;
        *(short*)(VtB + ((dh * 128 + skey * 2) ^ qz)) = (short)vv[j];
      }
    }
    __syncthreads();   // staging visible
    if (kt + 64 < LQ) {   // prefetch next K/V tile; hides under S/softmax/PV below
      const int kr = min(kt + 64 + skey, LQ - 1);
      kb = *(const bf16x8*)(Kg + ((size_t)(b * LQ + kr)) * DM + h * DH + sq * 8);
      vv = *(const bf16x8*)(Vg + ((size_t)(b * LQ + kr)) * DM + h * DH + sq * 8);
    }
    f32x4 s[4];
#pragma unroll
    for (int cb = 0; cb < 4; cb++) {
      const int key = cb * 16 + l15;
      const bf16x8 kf = *(const bf16x8*)(KsB + ((key * 64 + lc * 16) ^ ((key & 7) << 4)));
      const f32x4 z = {0.f, 0.f, 0.f, 0.f};
      s[cb] = __builtin_amdgcn_mfma_f32_16x16x32_bf16(qa, kf, z, 0, 0, 0);
    }
#pragma unroll
    for (int cb = 0; cb < 4; cb++)
      if (kt + cb * 16 + l15 >= LQ) {
        s[cb][0] = -1e30f; s[cb][1] = -1e30f; s[cb][2] = -1e30f; s[cb][3] = -1e30f;
      }
    float tm[4], fs[4], ps[4];
#pragma unroll
    for (int r = 0; r < 4; r++)
      tm[r] = fmaxf(fmaxf(s[0][r], s[1][r]), fmaxf(s[2][r], s[3][r]));
#pragma unroll
    for (int msk = 1; msk <= 8; msk <<= 1)
#pragma unroll
      for (int r = 0; r < 4; r++) tm[r] = fmaxf(tm[r], __shfl_xor(tm[r], msk));
#pragma unroll
    for (int r = 0; r < 4; r++) {
      const float nm = fmaxf(mrow[r], tm[r]);
      fs[r] = __expf(mrow[r] - nm);
      mrow[r] = nm;
    }
#pragma unroll
    for (int cb = 0; cb < 4; cb++)
#pragma unroll
      for (int r = 0; r < 4; r++) s[cb][r] = __expf(s[cb][r] - mrow[r]);
#pragma unroll
    for (int r = 0; r < 4; r++) ps[r] = (s[0][r] + s[1][r]) + (s[2][r] + s[3][r]);
#pragma unroll
    for (int msk = 1; msk <= 8; msk <<= 1)
#pragma unroll
      for (int r = 0; r < 4; r++) ps[r] += __shfl_xor(ps[r], msk);
#pragma unroll
    for (int r = 0; r < 4; r++) {
      lrow[r] = lrow[r] * fs[r] + ps[r];
      o0[r] *= fs[r]; o1[r] *= fs[r];
    }
#pragma unroll
    for (int cb = 0; cb < 4; cb++)
#pragma unroll
      for (int r = 0; r < 4; r++) {
        const int row = lc * 4 + r, col = cb * 16 + l15;
        *(short*)(PlB + ((row * 128 + col * 2) ^ ((row & 7) << 4))) = (short)f2bf(s[cb][r]);
      }
#pragma unroll
    for (int ks2 = 0; ks2 < 2; ks2++) {
      const int koff2 = (ks2 * 32 + lc * 8) * 2;
      const bf16x8 pa = *(const bf16x8*)(PlB + ((l15 * 128 + koff2) ^ ((l15 & 7) << 4)));
      {
        const int dh = l15;
        const int qz = ((dh & 7) ^ (((dh >> 3) & 3) << 1)) << 4;
        const bf16x8 vf = *(const bf16x8*)(VtB + ((dh * 128 + koff2) ^ qz));
        o0 = __builtin_amdgcn_mfma_f32_16x16x32_bf16(pa, vf, o0, 0, 0, 0);
      }
      {
        const int dh = 16 + l15;
        const int qz = ((dh & 7) ^ (((dh >> 3) & 3) << 1)) << 4;
        const bf16x8 vf = *(const bf16x8*)(VtB + ((dh * 128 + koff2) ^ qz));
        o1 = __builtin_amdgcn_mfma_f32_16x16x32_bf16(pa, vf, o1, 0, 0, 0);
      }
    }
  }
#pragma unroll
  for (int r = 0; r < 4; r++) {
    const int qrow = q0 + w * 16 + lc * 4 + r;
    if (qrow < LQ) {
      const float inv = 1.f / lrow[r];
      unsigned short* op = O + ((size_t)(b * LQ + qrow)) * DM + h * DH;
      op[l15] = f2bf(o0[r] * inv);
      op[16 + l15] = f2bf(o1[r] * inv);
    }
  }
}

// ---------------- MS-deform sampling: 8 threads per (b,q,h), 4 channels each; bf16 out ----------------
__global__ __launch_bounds__(256) void sample_kernel(const unsigned short* __restrict__ value,
                                                     const float* __restrict__ ref,
                                                     const float* __restrict__ off,
                                                     const float* __restrict__ att,
                                                     unsigned short* __restrict__ out) {
  const int t = blockIdx.x * 256 + threadIdx.x;   // < NB*LQ*NH*8 = 460800
  const int d4 = t & 7;
  const int h = (t >> 3) & 7;
  const int qb = t >> 6;                           // b*LQ + q
  const int b = qb / LQ;
  const int HLs[4] = {100, 50, 25, 13};
  const int STs[4] = {0, 10000, 12500, 13125};
  const float* rp = ref + (size_t)qb * (NL * 2);
  const float* op = off + (size_t)qb * DM + h * (NL * NP * 2);
  const float* ap = att + (size_t)qb * (NH * NL * NP) + h * (NL * NP);
  const unsigned short* vb = value + (size_t)b * LIN * DM + h * DH + d4 * 4;

  float aw[16];
#pragma unroll
  for (int i = 0; i < 4; i++) {
    const float4 a4 = ((const float4*)ap)[i];
    aw[4 * i] = a4.x; aw[4 * i + 1] = a4.y; aw[4 * i + 2] = a4.z; aw[4 * i + 3] = a4.w;
  }
  float am = aw[0];
#pragma unroll
  for (int i = 1; i < 16; i++) am = fmaxf(am, aw[i]);
  float asum = 0.f;
#pragma unroll
  for (int i = 0; i < 16; i++) { aw[i] = __expf(aw[i] - am); asum += aw[i]; }
  const float ainv = 1.f / asum;

  float acc[4] = {};
#pragma unroll
  for (int l = 0; l < NL; l++) {
    const int Hl = HLs[l], Wl = HLs[l], st = STs[l];
    const float rx = rp[l * 2], ry = rp[l * 2 + 1];
#pragma unroll
    for (int p = 0; p < NP; p++) {
      const float2 o2 = ((const float2*)op)[l * NP + p];
      const float a = aw[l * NP + p] * ainv;
      const float locx = rx + o2.x / (float)Wl;
      const float locy = ry + o2.y / (float)Hl;
      const float x = locx * (float)Wl - 0.5f;
      const float y = locy * (float)Hl - 0.5f;
      const float xf = floorf(x), yf = floorf(y);
      const float fx = x - xf, fy = y - yf;
      const int x0 = (int)xf, y0 = (int)yf;
      const int x1 = x0 + 1, y1 = y0 + 1;
      const float vx0 = (x0 >= 0 && x0 < Wl) ? 1.f : 0.f;
      const float vx1 = (x1 >= 0 && x1 < Wl) ? 1.f : 0.f;
      const float vy0 = (y0 >= 0 && y0 < Hl) ? 1.f : 0.f;
      const float vy1 = (y1 >= 0 && y1 < Hl) ? 1.f : 0.f;
      const int cx0 = min(max(x0, 0), Wl - 1), cx1 = min(max(x1, 0), Wl - 1);
      const int cy0 = min(max(y0, 0), Hl - 1), cy1 = min(max(y1, 0), Hl - 1);
      const float w00 = a * (1.f - fx) * (1.f - fy) * vx0 * vy0;
      const float w10 = a * fx * (1.f - fy) * vx1 * vy0;
      const float w01 = a * (1.f - fx) * fy * vx0 * vy1;
      const float w11 = a * fx * fy * vx1 * vy1;
      const unsigned short* r0 = vb + (size_t)(st + cy0 * Wl) * DM;
      const unsigned short* r1 = vb + (size_t)(st + cy1 * Wl) * DM;
      const uint2 g00 = *(const uint2*)(r0 + (size_t)cx0 * DM);
      const uint2 g10 = *(const uint2*)(r0 + (size_t)cx1 * DM);
      const uint2 g01 = *(const uint2*)(r1 + (size_t)cx0 * DM);
      const uint2 g11 = *(const uint2*)(r1 + (size_t)cx1 * DM);
      const unsigned u00[2] = {g00.x, g00.y};
      const unsigned u10[2] = {g10.x, g10.y};
      const unsigned u01[2] = {g01.x, g01.y};
      const unsigned u11[2] = {g11.x, g11.y};
#pragma unroll
      for (int i = 0; i < 2; i++) {
        acc[2 * i]     += w00 * __uint_as_float(u00[i] << 16) + w10 * __uint_as_float(u10[i] << 16)
                        + w01 * __uint_as_float(u01[i] << 16) + w11 * __uint_as_float(u11[i] << 16);
        acc[2 * i + 1] += w00 * __uint_as_float(u00[i] & 0xFFFF0000u) + w10 * __uint_as_float(u10[i] & 0xFFFF0000u)
                        + w01 * __uint_as_float(u01[i] & 0xFFFF0000u) + w11 * __uint_as_float(u11[i] & 0xFFFF0000u);
      }
    }
  }
  uint2 ov;
  ov.x = (unsigned)f2bf(acc[0]) | ((unsigned)f2bf(acc[1]) << 16);
  ov.y = (unsigned)f2bf(acc[2]) | ((unsigned)f2bf(acc[3]) << 16);
  *(uint2*)(out + (size_t)t * 4) = ov;
}

// ---------------- fused residual-add + LayerNorm, 4 rows per block (1 wave/row) ----------------
__global__ __launch_bounds__(256) void ln_kernel(const float* __restrict__ A,
                                                 const float* __restrict__ R,
                                                 const float* __restrict__ g,
                                                 const float* __restrict__ be,
                                                 float* __restrict__ out) {
  const int row = blockIdx.x * 4 + (threadIdx.x >> 6);
  const int t = threadIdx.x & 63;
  const float4 va = ((const float4*)(A + (size_t)row * DM))[t];
  const float4 vr = ((const float4*)(R + (size_t)row * DM))[t];
  const float x0 = va.x + vr.x, x1 = va.y + vr.y, x2 = va.z + vr.z, x3 = va.w + vr.w;
  float s = x0 + x1 + x2 + x3;
  float ss = x0 * x0 + x1 * x1 + x2 * x2 + x3 * x3;
#pragma unroll
  for (int o = 1; o < 64; o <<= 1) { s += __shfl_xor(s, o); ss += __shfl_xor(ss, o); }
  const float mean = s * (1.f / DM);
  const float var = ss * (1.f / DM) - mean * mean;
  const float rstd = rsqrtf(var + 1e-5f);
  const float4 vg = ((const float4*)g)[t];
  const float4 vb = ((const float4*)be)[t];
  float4 o4;
  o4.x = (x0 - mean) * rstd * vg.x + vb.x;
  o4.y = (x1 - mean) * rstd * vg.y + vb.y;
  o4.z = (x2 - mean) * rstd * vg.z + vb.z;
  o4.w = (x3 - mean) * rstd * vg.w + vb.w;
  ((float4*)(out + (size_t)row * DM))[t] = o4;
}

extern "C" void kernel_launch(void* const* d_in, const int* in_sizes, int n_in,
                              void* d_out, int out_size, void* d_ws, size_t ws_size,
                              hipStream_t stream) {
  const float* tgt  = (const float*)d_in[1];
  const float* qpos = (const float*)d_in[2];
  const float* ref  = (const float*)d_in[3];
  const float* src  = (const float*)d_in[4];
  const float* wq = (const float*)d_in[8];  const float* bq = (const float*)d_in[9];
  const float* wk = (const float*)d_in[10]; const float* bk = (const float*)d_in[11];
  const float* wv = (const float*)d_in[12]; const float* bv = (const float*)d_in[13];
  const float* wo = (const float*)d_in[14]; const float* bo = (const float*)d_in[15];
  const float* w_val = (const float*)d_in[16]; const float* b_val = (const float*)d_in[17];
  const float* w_off = (const float*)d_in[18]; const float* b_off = (const float*)d_in[19];
  const float* w_att = (const float*)d_in[20]; const float* b_att = (const float*)d_in[21];
  const float* w_out = (const float*)d_in[22]; const float* b_out = (const float*)d_in[23];
  const float* ln1g = (const float*)d_in[24]; const float* ln1b = (const float*)d_in[25];
  const float* ln2g = (const float*)d_in[26]; const float* ln2b = (const float*)d_in[27];
  const float* ln3g = (const float*)d_in[28]; const float* ln3b = (const float*)d_in[29];
  const float* w1 = (const float*)d_in[30]; const float* b1 = (const float*)d_in[31];
  const float* w2 = (const float*)d_in[32]; const float* b2 = (const float*)d_in[33];

  const size_t S = (size_t)MROW * DM;
  const size_t VAL_F = (size_t)NVAL * DM;
  float* ws = (float*)d_ws;
  float* value = ws;                 // bf16: floats [0, VAL_F/2)
  unsigned short* wp = (unsigned short*)(ws + VAL_F / 2);  // ~2 MB packed weights
  float* B0   = ws + VAL_F;
  unsigned short* Qb = (unsigned short*)(B0 + 1 * S);   // bf16
  unsigned short* Kb = (unsigned short*)(B0 + 2 * S);   // bf16
  unsigned short* Vb = (unsigned short*)(B0 + 3 * S);   // bf16
  unsigned short* Ob = (unsigned short*)(B0 + 4 * S);   // bf16
  float* tmp  = B0 + 5 * S;
  float* x1   = B0 + 0 * S;
  float* offb = B0 + 2 * S;
  float* attb = B0 + 3 * S;
  unsigned short* samp = (unsigned short*)(B0 + 4 * S); // bf16 (Ob dead by then)
  float* x2   = B0 + 6 * S;
  unsigned short* hffn = (unsigned short*)(B0 + 1 * S); // bf16, spans [1S,3S)

  const float qscale = 0.17677669529663687f;  // 1/sqrt(32)
  const dim3 blk(256);
  const dim3 gQ(DM / 64, (MROW + 63) / 64);            // (4,113)

  // ---- weight pack (one dispatch, all 10 matrices) ----
  pack_all<<<dim3(WP_TOT / 256), blk, 0, stream>>>(w_val, wq, wk, wv, wo, w_off, w_att,
                                                   w_out, w1, w2, wp);

  // ---- self-attention ----
  gemm_qkv<<<dim3(4, 113, 3), blk, 0, stream>>>(tgt, qpos, wp, bq, bk, bv,
                                                Qb, Kb, Vb, qscale);
  attn_mfma<<<dim3((LQ + 63) / 64, NH, NB), blk, 0, stream>>>(Qb, Kb, Vb, Ob);
  gemm_fused<<<gQ, blk, 0, stream>>>(Ob, wp + WP_O, bo, tmp, MROW, DM, DM, 1.f, 0, 1, 0);
  ln_kernel<<<dim3(MROW / 4), blk, 0, stream>>>(tmp, tgt, ln2g, ln2b, x1);

  // ---- deformable cross-attention ----
  value_gemm6<<<dim3(GVAL2), blk, 0, stream>>>(src, wp + WP_VAL, b_val,
                                               (unsigned short*)value, NVAL);
  gemm_offatt<<<dim3(4, 113, 2), blk, 0, stream>>>(x1, qpos, wp, b_off, b_att, offb, attb);
  sample_kernel<<<dim3((MROW * NH * 8) / 256), blk, 0, stream>>>(
      (const unsigned short*)value, ref, offb, attb, samp);
  gemm_fused<<<gQ, blk, 0, stream>>>(samp, wp + WP_OUT, b_out, tmp, MROW, DM, DM,
                                     1.f, 0, 1, 0);
  ln_kernel<<<dim3(MROW / 4), blk, 0, stream>>>(tmp, x1, ln1g, ln1b, x2);

  // ---- FFN ----
  gemm_fused<<<dim3(DFFN / 64, 113), blk, 0, stream>>>(x2, wp + WP_W1, b1, hffn, MROW,
                                                       DFFN, DM, 1.f, 1, 0, 1);
  gemm_fused<<<gQ, blk, 0, stream>>>(hffn, wp + WP_W2, b2, tmp, MROW, DM, DFFN,
                                     1.f, 0, 1, 0);
  ln_kernel<<<dim3(MROW / 4), blk, 0, stream>>>(tmp, x2, ln3g, ln3b, (float*)d_out);
}

// Round 15
// 231.135 us; speedup vs baseline: 1.1233x; 1.0153x over previous
//
#include <hip/hip_runtime.h>
#include <math.h>

#define NB 8
#define LQ 900
#define DM 256
#define NH 8
#define DH 32
#define NL 4
#define NP 4
#define DFFN 1024
#define LIN 13294
#define NVAL (NB*LIN)      // 106352 rows for value projection
#define MROW (NB*LQ)       // 7200 rows for query-side matmuls
#define GVAL2 3324         // 1662 M-strips(64) x 2 N-halves(128)

// packed-weight segment offsets (shorts)
#define WP_VAL 0
#define WP_Q   65536
#define WP_K   131072
#define WP_V   196608
#define WP_O   262144
#define WP_OFF 327680
#define WP_ATT 393216
#define WP_OUT 425984
#define WP_W1  491520
#define WP_W2  753664
#define WP_TOT 1015808     // = 3968 * 256

typedef __attribute__((ext_vector_type(8))) short bf16x8;
typedef __attribute__((ext_vector_type(4))) float f32x4;

__device__ __forceinline__ unsigned short f2bf(float x) {
  unsigned u = __float_as_uint(x);
  u += 0x7FFFu + ((u >> 16) & 1u);   // round-to-nearest-even
  return (unsigned short)(u >> 16);
}

// ---------------- pack ALL weights: fp32 [k][n] -> bf16 tiled [kt][n][32], pre-swizzled ----------------
__global__ __launch_bounds__(256) void pack_all(
    const float* __restrict__ w_val, const float* __restrict__ wq,
    const float* __restrict__ wk, const float* __restrict__ wv,
    const float* __restrict__ wo, const float* __restrict__ w_off,
    const float* __restrict__ w_att, const float* __restrict__ w_out,
    const float* __restrict__ w1, const float* __restrict__ w2,
    unsigned short* __restrict__ Wp) {
  const int idx = blockIdx.x * 256 + threadIdx.x;
  const float* src; int r, logN;
  if (idx < WP_Q)        { src = w_val; r = idx;          logN = 8; }
  else if (idx < WP_K)   { src = wq;    r = idx - WP_Q;   logN = 8; }
  else if (idx < WP_V)   { src = wk;    r = idx - WP_K;   logN = 8; }
  else if (idx < WP_O)   { src = wv;    r = idx - WP_V;   logN = 8; }
  else if (idx < WP_OFF) { src = wo;    r = idx - WP_O;   logN = 8; }
  else if (idx < WP_ATT) { src = w_off; r = idx - WP_OFF; logN = 8; }
  else if (idx < WP_OUT) { src = w_att; r = idx - WP_ATT; logN = 7; }
  else if (idx < WP_W1)  { src = w_out; r = idx - WP_OUT; logN = 8; }
  else if (idx < WP_W2)  { src = w1;    r = idx - WP_W1;  logN = 10; }
  else                   { src = w2;    r = idx - WP_W2;  logN = 8; }
  const int N = 1 << logN;
  const int e = r & 7, cs = (r >> 3) & 3;
  const int n = (r >> 5) & (N - 1);
  const int kt = r >> (5 + logN);
  const int c = cs ^ ((n >> 1) & 3);
  const int k = kt * 32 + c * 8 + e;
  Wp[idx] = f2bf(src[(size_t)k * N + n]);
}

// ---------------- value GEMM v7: v4 structure, ALL A preloaded to regs at entry ----------------
__global__ __launch_bounds__(256) void value_gemm7(const float* __restrict__ A,
                                                   const unsigned short* __restrict__ Wp,
                                                   const float* __restrict__ bias,
                                                   unsigned short* __restrict__ C,
                                                   int M) {
  __shared__ char lds[24576];
  short* As = (short*)lds;             // 2 x 2048 shorts (64x32, chunk-swizzled)
  short* Bs = (short*)(lds + 8192);    // 2 x 4096 shorts (128x32, linear pre-swizzled)
  const int tid = threadIdx.x;
  const int lane = tid & 63, w = tid >> 6;
  const int wr = w >> 1, wc = w & 1;
  const int l15 = lane & 15, lc = lane >> 4;
  const int nwg = gridDim.x;
  const int qq = nwg >> 3, rr = nwg & 7;
  const int xcd = blockIdx.x & 7, pos = blockIdx.x >> 3;
  const int wgid = (xcd < rr ? xcd * (qq + 1) : rr * (qq + 1) + (xcd - rr) * qq) + pos;
  const int m0 = (wgid >> 1) * 64, n0 = (wgid & 1) * 128;
  const int ar = tid >> 2, ac = tid & 3;
  const int arow = min(m0 + ar, M - 1);
  f32x4 acc[2][4] = {};
  // ---- preload ALL A for this thread: 8 K-tiles x 2 float4 (entire row slice) ----
  float4 pa[8][2];
  {
    const float* ap_ = A + (size_t)arow * 256 + ac * 8;
#pragma unroll
    for (int kt = 0; kt < 8; kt++) {
      pa[kt][0] = ((const float4*)(ap_ + kt * 32))[0];
      pa[kt][1] = ((const float4*)(ap_ + kt * 32))[1];
    }
  }
  uint4 pb0, pb1;
  {
    const unsigned short* bp_ = Wp + ((size_t)n0) * 32 + tid * 16;
    pb0 = ((const uint4*)bp_)[0]; pb1 = ((const uint4*)bp_)[1];
  }
#pragma unroll
  for (int kt = 0; kt < 8; kt++) {
    short* Ac = As + (kt & 1) * 2048;
    short* Bc = Bs + (kt & 1) * 4096;
    {
      bf16x8 av;
      av[0] = (short)f2bf(pa[kt][0].x); av[1] = (short)f2bf(pa[kt][0].y);
      av[2] = (short)f2bf(pa[kt][0].z); av[3] = (short)f2bf(pa[kt][0].w);
      av[4] = (short)f2bf(pa[kt][1].x); av[5] = (short)f2bf(pa[kt][1].y);
      av[6] = (short)f2bf(pa[kt][1].z); av[7] = (short)f2bf(pa[kt][1].w);
      *(bf16x8*)&Ac[ar * 32 + ((ac ^ ((ar >> 1) & 3)) << 3)] = av;
      *(uint4*)&Bc[tid * 16] = pb0;
      *(uint4*)&Bc[tid * 16 + 8] = pb1;
    }
    __syncthreads();
    if (kt + 1 < 8) {   // prefetch next B tile (L2-hot) under this tile's MFMAs
      const unsigned short* bp_ = Wp + ((size_t)((kt + 1) * 256 + n0)) * 32 + tid * 16;
      pb0 = ((const uint4*)bp_)[0]; pb1 = ((const uint4*)bp_)[1];
    }
    bf16x8 af[2], bq[4];
#pragma unroll
    for (int i = 0; i < 2; i++) {
      const int row = wr * 32 + i * 16 + l15;
      af[i] = *(const bf16x8*)&Ac[row * 32 + ((lc ^ ((row >> 1) & 3)) << 3)];
    }
#pragma unroll
    for (int q = 0; q < 4; q++) {
      const int col = wc * 64 + q * 16 + l15;
      bq[q] = *(const bf16x8*)&Bc[col * 32 + ((lc ^ ((col >> 1) & 3)) << 3)];
    }
#pragma unroll
    for (int i = 0; i < 2; i++)
#pragma unroll
      for (int q = 0; q < 4; q++)
        acc[i][q] = __builtin_amdgcn_mfma_f32_16x16x32_bf16(af[i], bq[q], acc[i][q], 0, 0, 0);
  }
  // ---- epilogue: bias + bf16 via per-wave strip, coalesced 16B stores ----
  __syncthreads();
  short* strip = (short*)lds + w * 2176;   // 32 rows x 68 shorts
  float bv[4];
#pragma unroll
  for (int q = 0; q < 4; q++) bv[q] = bias[n0 + wc * 64 + q * 16 + l15];
#pragma unroll
  for (int i = 0; i < 2; i++)
#pragma unroll
    for (int q = 0; q < 4; q++)
#pragma unroll
      for (int r = 0; r < 4; r++)
        strip[(i * 16 + lc * 4 + r) * 68 + q * 16 + l15] = (short)f2bf(acc[i][q][r] + bv[q]);
  __syncthreads();
#pragma unroll
  for (int p = 0; p < 4; p++) {
    const int row = p * 8 + (lane >> 3), c8 = lane & 7;
    const bf16x8 v = *(const bf16x8*)&strip[row * 68 + c8 * 8];
    const int grow = m0 + wr * 32 + row;
    if (grow < M)
      *(bf16x8*)(C + (size_t)grow * 256 + n0 + wc * 64 + c8 * 8) = v;
  }
}

// ---------------- shared GEMM body: 64x64 tile, packed B, pipelined (1 barrier/iter) ----------------
__device__ __forceinline__ void gemm_body(const void* Aptr, const float* A2,
                                          const unsigned short* __restrict__ Wp,
                                          const float* __restrict__ bias, void* Cptr,
                                          int M, int Nn, int K, float scale, int relu,
                                          int a_bf16, int out_bf16, int m0, int n0,
                                          short* As, short* Bs) {
  const int tid = threadIdx.x;
  const int lane = tid & 63, w = tid >> 6;
  const int wr = w >> 1, wc = w & 1;
  const int ar = tid >> 2, ac = tid & 3;
  const int l15 = lane & 15, lc = lane >> 4;
  const int arow = min(m0 + ar, M - 1);
  f32x4 acc[2][2] = {};
  float4 pa0, pa1, pc0, pc1; bf16x8 pav; uint4 pb;
  {
    if (a_bf16) {
      pav = *(const bf16x8*)((const unsigned short*)Aptr + (size_t)arow * K + ac * 8);
    } else {
      const float* ap_ = (const float*)Aptr + (size_t)arow * K + ac * 8;
      pa0 = ((const float4*)ap_)[0]; pa1 = ((const float4*)ap_)[1];
      if (A2) {
        const float* cp_ = A2 + (size_t)arow * K + ac * 8;
        pc0 = ((const float4*)cp_)[0]; pc1 = ((const float4*)cp_)[1];
      }
    }
    pb = *(const uint4*)(Wp + ((size_t)n0) * 32 + tid * 8);
  }
  for (int kt = 0; kt < K; kt += 32) {
    short* Ac = As + ((kt >> 5) & 1) * 2048;
    short* Bc = Bs + ((kt >> 5) & 1) * 2048;
    {
      bf16x8 av;
      if (a_bf16) {
        av = pav;
      } else {
        float4 a0 = pa0, a1 = pa1;
        if (A2) {
          a0.x += pc0.x; a0.y += pc0.y; a0.z += pc0.z; a0.w += pc0.w;
          a1.x += pc1.x; a1.y += pc1.y; a1.z += pc1.z; a1.w += pc1.w;
        }
        av[0] = (short)f2bf(a0.x); av[1] = (short)f2bf(a0.y);
        av[2] = (short)f2bf(a0.z); av[3] = (short)f2bf(a0.w);
        av[4] = (short)f2bf(a1.x); av[5] = (short)f2bf(a1.y);
        av[6] = (short)f2bf(a1.z); av[7] = (short)f2bf(a1.w);
      }
      *(bf16x8*)&Ac[ar * 32 + ((ac ^ ((ar >> 1) & 3)) << 3)] = av;
      *(uint4*)&Bc[tid * 8] = pb;
    }
    __syncthreads();
    if (kt + 32 < K) {   // prefetch next tile into regs
      if (a_bf16) {
        pav = *(const bf16x8*)((const unsigned short*)Aptr + (size_t)arow * K + kt + 32 + ac * 8);
      } else {
        const float* ap_ = (const float*)Aptr + (size_t)arow * K + kt + 32 + ac * 8;
        pa0 = ((const float4*)ap_)[0]; pa1 = ((const float4*)ap_)[1];
        if (A2) {
          const float* cp_ = A2 + (size_t)arow * K + kt + 32 + ac * 8;
          pc0 = ((const float4*)cp_)[0]; pc1 = ((const float4*)cp_)[1];
        }
      }
      pb = *(const uint4*)(Wp + ((size_t)(((kt >> 5) + 1) * Nn + n0)) * 32 + tid * 8);
    }
    bf16x8 af[2], bf[2];
#pragma unroll
    for (int i = 0; i < 2; i++) {
      const int row = wr * 32 + i * 16 + l15;
      af[i] = *(const bf16x8*)&Ac[row * 32 + ((lc ^ ((row >> 1) & 3)) << 3)];
      const int col = wc * 32 + i * 16 + l15;
      bf[i] = *(const bf16x8*)&Bc[col * 32 + ((lc ^ ((col >> 1) & 3)) << 3)];
    }
#pragma unroll
    for (int i = 0; i < 2; i++)
#pragma unroll
      for (int j = 0; j < 2; j++)
        acc[i][j] = __builtin_amdgcn_mfma_f32_16x16x32_bf16(af[i], bf[j], acc[i][j], 0, 0, 0);
  }
#pragma unroll
  for (int i = 0; i < 2; i++) {
    const int row0 = m0 + wr * 32 + i * 16 + lc * 4;
#pragma unroll
    for (int j = 0; j < 2; j++) {
      const int col = n0 + wc * 32 + j * 16 + l15;
      const float bv = bias[col];
#pragma unroll
      for (int r = 0; r < 4; r++) {
        const int row = row0 + r;
        if (row < M) {
          float v = (acc[i][j][r] + bv) * scale;
          if (relu) v = fmaxf(v, 0.f);
          if (out_bf16)
            ((unsigned short*)Cptr)[(size_t)row * Nn + col] = f2bf(v);
          else
            ((float*)Cptr)[(size_t)row * Nn + col] = v;
        }
      }
    }
  }
}

// ---------------- fused QKV projection: z selects Q/K/V; add(tgt,qpos) fused; bf16 out ----------------
__global__ __launch_bounds__(256) void gemm_qkv(const float* __restrict__ tgt,
                                                const float* __restrict__ qpos,
                                                const unsigned short* __restrict__ Wp,
                                                const float* __restrict__ bq_,
                                                const float* __restrict__ bk_,
                                                const float* __restrict__ bv_,
                                                unsigned short* Qb, unsigned short* Kb,
                                                unsigned short* Vb, float qscale) {
  __shared__ short As[2 * 2048];
  __shared__ short Bs[2 * 2048];
  const int z = blockIdx.z;
  const unsigned short* W = Wp + (z == 0 ? WP_Q : z == 1 ? WP_K : WP_V);
  const float* bias = (z == 0) ? bq_ : (z == 1) ? bk_ : bv_;
  unsigned short* C = (z == 0) ? Qb : (z == 1) ? Kb : Vb;
  const float* A2 = (z == 2) ? nullptr : qpos;
  gemm_body(tgt, A2, W, bias, C, MROW, DM, DM, (z == 0) ? qscale : 1.f, 0, 0, 1,
            blockIdx.y * 64, blockIdx.x * 64, As, Bs);
}

// ---------------- fused offset+attention-logit projection: add(x1,qpos) fused ----------------
__global__ __launch_bounds__(256) void gemm_offatt(const float* __restrict__ x1,
                                                   const float* __restrict__ qpos,
                                                   const unsigned short* __restrict__ Wp,
                                                   const float* __restrict__ b_off,
                                                   const float* __restrict__ b_att,
                                                   float* offb, float* attb) {
  const int z = blockIdx.z;
  if (z == 1 && blockIdx.x >= 2) return;
  __shared__ short As[2 * 2048];
  __shared__ short Bs[2 * 2048];
  const unsigned short* W = Wp + (z ? WP_ATT : WP_OFF);
  const float* bias = z ? b_att : b_off;
  float* C = z ? attb : offb;
  const int Nn = z ? 128 : 256;
  gemm_body(x1, qpos, W, bias, C, MROW, Nn, DM, 1.f, 0, 0, 0,
            blockIdx.y * 64, blockIdx.x * 64, As, Bs);
}

// ---------------- generic GEMM dispatch (packed B) ----------------
__global__ __launch_bounds__(256) void gemm_fused(const void* A, const unsigned short* Wp,
                                                  const float* bias, void* C, int M, int Nn,
                                                  int K, float scale, int relu, int a_bf16,
                                                  int out_bf16) {
  __shared__ short As[2 * 2048];
  __shared__ short Bs[2 * 2048];
  gemm_body(A, nullptr, Wp, bias, C, M, Nn, K, scale, relu, a_bf16, out_bf16,
            blockIdx.y * 64, blockIdx.x * 64, As, Bs);
}

// ---------------- MFMA flash attention (bf16 in/out, next-tile reg prefetch) ----------------
__global__ __launch_bounds__(256) void attn_mfma(const unsigned short* __restrict__ Qg,
                                                 const unsigned short* __restrict__ Kg,
                                                 const unsigned short* __restrict__ Vg,
                                                 unsigned short* __restrict__ O) {
  __shared__ short Ks[2048];
  __shared__ short Vt[2048];
  __shared__ short Pl[4096];
  const int tid = threadIdx.x;
  const int lane = tid & 63, w = tid >> 6;
  const int l15 = lane & 15, lc = lane >> 4;
  const int h = blockIdx.y, b = blockIdx.z;
  const int q0 = blockIdx.x * 64;
  char* KsB = (char*)Ks; char* VtB = (char*)Vt; char* PlB = (char*)Pl + w * 2048;

  bf16x8 qa;
  {
    const int qrow = min(q0 + w * 16 + l15, LQ - 1);
    qa = *(const bf16x8*)(Qg + ((size_t)(b * LQ + qrow)) * DM + h * DH + lc * 8);
  }
  f32x4 o0 = {0.f, 0.f, 0.f, 0.f}, o1 = {0.f, 0.f, 0.f, 0.f};
  float mrow[4], lrow[4];
#pragma unroll
  for (int r = 0; r < 4; r++) { mrow[r] = -1e30f; lrow[r] = 0.f; }
  const int skey = tid >> 2, sq = tid & 3;

  // preload tile 0
  bf16x8 kb, vv;
  {
    const int kr = min(skey, LQ - 1);
    kb = *(const bf16x8*)(Kg + ((size_t)(b * LQ + kr)) * DM + h * DH + sq * 8);
    vv = *(const bf16x8*)(Vg + ((size_t)(b * LQ + kr)) * DM + h * DH + sq * 8);
  }
  for (int kt = 0; kt < LQ; kt += 64) {
    __syncthreads();   // prev tile's LDS reads done
    {
      *(bf16x8*)(KsB + ((skey * 64 + sq * 16) ^ ((skey & 7) << 4))) = kb;
#pragma unroll
      for (int j = 0; j < 8; j++) {
        const int dh = sq * 8 + j;
        const int qz = ((dh & 7) ^ (((dh >> 3) & 3) << 1)) << 4;
        *(short*)(VtB + ((dh * 128 + skey * 2) ^ qz)) = (short)vv[j];
      }
    }
    __syncthreads();   // staging visible
    if (kt + 64 < LQ) {   // prefetch next K/V tile; hides under S/softmax/PV below
      const int kr = min(kt + 64 + skey, LQ - 1);
      kb = *(const bf16x8*)(Kg + ((size_t)(b * LQ + kr)) * DM + h * DH + sq * 8);
      vv = *(const bf16x8*)(Vg + ((size_t)(b * LQ + kr)) * DM + h * DH + sq * 8);
    }
    f32x4 s[4];
#pragma unroll
    for (int cb = 0; cb < 4; cb++) {
      const int key = cb * 16 + l15;
      const bf16x8 kf = *(const bf16x8*)(KsB + ((key * 64 + lc * 16) ^ ((key & 7) << 4)));
      const f32x4 z = {0.f, 0.f, 0.f, 0.f};
      s[cb] = __builtin_amdgcn_mfma_f32_16x16x32_bf16(qa, kf, z, 0, 0, 0);
    }
#pragma unroll
    for (int cb = 0; cb < 4; cb++)
      if (kt + cb * 16 + l15 >= LQ) {
        s[cb][0] = -1e30f; s[cb][1] = -1e30f; s[cb][2] = -1e30f; s[cb][3] = -1e30f;
      }
    float tm[4], fs[4], ps[4];
#pragma unroll
    for (int r = 0; r < 4; r++)
      tm[r] = fmaxf(fmaxf(s[0][r], s[1][r]), fmaxf(s[2][r], s[3][r]));
#pragma unroll
    for (int msk = 1; msk <= 8; msk <<= 1)
#pragma unroll
      for (int r = 0; r < 4; r++) tm[r] = fmaxf(tm[r], __shfl_xor(tm[r], msk));
#pragma unroll
    for (int r = 0; r < 4; r++) {
      const float nm = fmaxf(mrow[r], tm[r]);
      fs[r] = __expf(mrow[r] - nm);
      mrow[r] = nm;
    }
#pragma unroll
    for (int cb = 0; cb < 4; cb++)
#pragma unroll
      for (int r = 0; r < 4; r++) s[cb][r] = __expf(s[cb][r] - mrow[r]);
#pragma unroll
    for (int r = 0; r < 4; r++) ps[r] = (s[0][r] + s[1][r]) + (s[2][r] + s[3][r]);
#pragma unroll
    for (int msk = 1; msk <= 8; msk <<= 1)
#pragma unroll
      for (int r = 0; r < 4; r++) ps[r] += __shfl_xor(ps[r], msk);
#pragma unroll
    for (int r = 0; r < 4; r++) {
      lrow[r] = lrow[r] * fs[r] + ps[r];
      o0[r] *= fs[r]; o1[r] *= fs[r];
    }
#pragma unroll
    for (int cb = 0; cb < 4; cb++)
#pragma unroll
      for (int r = 0; r < 4; r++) {
        const int row = lc * 4 + r, col = cb * 16 + l15;
        *(short*)(PlB + ((row * 128 + col * 2) ^ ((row & 7) << 4))) = (short)f2bf(s[cb][r]);
      }
#pragma unroll
    for (int ks2 = 0; ks2 < 2; ks2++) {
      const int koff2 = (ks2 * 32 + lc * 8) * 2;
      const bf16x8 pa = *(const bf16x8*)(PlB + ((l15 * 128 + koff2) ^ ((l15 & 7) << 4)));
      {
        const int dh = l15;
        const int qz = ((dh & 7) ^ (((dh >> 3) & 3) << 1)) << 4;
        const bf16x8 vf = *(const bf16x8*)(VtB + ((dh * 128 + koff2) ^ qz));
        o0 = __builtin_amdgcn_mfma_f32_16x16x32_bf16(pa, vf, o0, 0, 0, 0);
      }
      {
        const int dh = 16 + l15;
        const int qz = ((dh & 7) ^ (((dh >> 3) & 3) << 1)) << 4;
        const bf16x8 vf = *(const bf16x8*)(VtB + ((dh * 128 + koff2) ^ qz));
        o1 = __builtin_amdgcn_mfma_f32_16x16x32_bf16(pa, vf, o1, 0, 0, 0);
      }
    }
  }
#pragma unroll
  for (int r = 0; r < 4; r++) {
    const int qrow = q0 + w * 16 + lc * 4 + r;
    if (qrow < LQ) {
      const float inv = 1.f / lrow[r];
      unsigned short* op = O + ((size_t)(b * LQ + qrow)) * DM + h * DH;
      op[l15] = f2bf(o0[r] * inv);
      op[16 + l15] = f2bf(o1[r] * inv);
    }
  }
}

// ---------------- MS-deform sampling: 8 threads per (b,q,h), 4 channels each; bf16 out ----------------
__global__ __launch_bounds__(256) void sample_kernel(const unsigned short* __restrict__ value,
                                                     const float* __restrict__ ref,
                                                     const float* __restrict__ off,
                                                     const float* __restrict__ att,
                                                     unsigned short* __restrict__ out) {
  const int t = blockIdx.x * 256 + threadIdx.x;   // < NB*LQ*NH*8 = 460800
  const int d4 = t & 7;
  const int h = (t >> 3) & 7;
  const int qb = t >> 6;                           // b*LQ + q
  const int b = qb / LQ;
  const int HLs[4] = {100, 50, 25, 13};
  const int STs[4] = {0, 10000, 12500, 13125};
  const float* rp = ref + (size_t)qb * (NL * 2);
  const float* op = off + (size_t)qb * DM + h * (NL * NP * 2);
  const float* ap = att + (size_t)qb * (NH * NL * NP) + h * (NL * NP);
  const unsigned short* vb = value + (size_t)b * LIN * DM + h * DH + d4 * 4;

  float aw[16];
#pragma unroll
  for (int i = 0; i < 4; i++) {
    const float4 a4 = ((const float4*)ap)[i];
    aw[4 * i] = a4.x; aw[4 * i + 1] = a4.y; aw[4 * i + 2] = a4.z; aw[4 * i + 3] = a4.w;
  }
  float am = aw[0];
#pragma unroll
  for (int i = 1; i < 16; i++) am = fmaxf(am, aw[i]);
  float asum = 0.f;
#pragma unroll
  for (int i = 0; i < 16; i++) { aw[i] = __expf(aw[i] - am); asum += aw[i]; }
  const float ainv = 1.f / asum;

  float acc[4] = {};
#pragma unroll
  for (int l = 0; l < NL; l++) {
    const int Hl = HLs[l], Wl = HLs[l], st = STs[l];
    const float rx = rp[l * 2], ry = rp[l * 2 + 1];
#pragma unroll
    for (int p = 0; p < NP; p++) {
      const float2 o2 = ((const float2*)op)[l * NP + p];
      const float a = aw[l * NP + p] * ainv;
      const float locx = rx + o2.x / (float)Wl;
      const float locy = ry + o2.y / (float)Hl;
      const float x = locx * (float)Wl - 0.5f;
      const float y = locy * (float)Hl - 0.5f;
      const float xf = floorf(x), yf = floorf(y);
      const float fx = x - xf, fy = y - yf;
      const int x0 = (int)xf, y0 = (int)yf;
      const int x1 = x0 + 1, y1 = y0 + 1;
      const float vx0 = (x0 >= 0 && x0 < Wl) ? 1.f : 0.f;
      const float vx1 = (x1 >= 0 && x1 < Wl) ? 1.f : 0.f;
      const float vy0 = (y0 >= 0 && y0 < Hl) ? 1.f : 0.f;
      const float vy1 = (y1 >= 0 && y1 < Hl) ? 1.f : 0.f;
      const int cx0 = min(max(x0, 0), Wl - 1), cx1 = min(max(x1, 0), Wl - 1);
      const int cy0 = min(max(y0, 0), Hl - 1), cy1 = min(max(y1, 0), Hl - 1);
      const float w00 = a * (1.f - fx) * (1.f - fy) * vx0 * vy0;
      const float w10 = a * fx * (1.f - fy) * vx1 * vy0;
      const float w01 = a * (1.f - fx) * fy * vx0 * vy1;
      const float w11 = a * fx * fy * vx1 * vy1;
      const unsigned short* r0 = vb + (size_t)(st + cy0 * Wl) * DM;
      const unsigned short* r1 = vb + (size_t)(st + cy1 * Wl) * DM;
      const uint2 g00 = *(const uint2*)(r0 + (size_t)cx0 * DM);
      const uint2 g10 = *(const uint2*)(r0 + (size_t)cx1 * DM);
      const uint2 g01 = *(const uint2*)(r1 + (size_t)cx0 * DM);
      const uint2 g11 = *(const uint2*)(r1 + (size_t)cx1 * DM);
      const unsigned u00[2] = {g00.x, g00.y};
      const unsigned u10[2] = {g10.x, g10.y};
      const unsigned u01[2] = {g01.x, g01.y};
      const unsigned u11[2] = {g11.x, g11.y};
#pragma unroll
      for (int i = 0; i < 2; i++) {
        acc[2 * i]     += w00 * __uint_as_float(u00[i] << 16) + w10 * __uint_as_float(u10[i] << 16)
                        + w01 * __uint_as_float(u01[i] << 16) + w11 * __uint_as_float(u11[i] << 16);
        acc[2 * i + 1] += w00 * __uint_as_float(u00[i] & 0xFFFF0000u) + w10 * __uint_as_float(u10[i] & 0xFFFF0000u)
                        + w01 * __uint_as_float(u01[i] & 0xFFFF0000u) + w11 * __uint_as_float(u11[i] & 0xFFFF0000u);
      }
    }
  }
  uint2 ov;
  ov.x = (unsigned)f2bf(acc[0]) | ((unsigned)f2bf(acc[1]) << 16);
  ov.y = (unsigned)f2bf(acc[2]) | ((unsigned)f2bf(acc[3]) << 16);
  *(uint2*)(out + (size_t)t * 4) = ov;
}

// ---------------- fused residual-add + LayerNorm, 4 rows per block (1 wave/row) ----------------
__global__ __launch_bounds__(256) void ln_kernel(const float* __restrict__ A,
                                                 const float* __restrict__ R,
                                                 const float* __restrict__ g,
                                                 const float* __restrict__ be,
                                                 float* __restrict__ out) {
  const int row = blockIdx.x * 4 + (threadIdx.x >> 6);
  const int t = threadIdx.x & 63;
  const float4 va = ((const float4*)(A + (size_t)row * DM))[t];
  const float4 vr = ((const float4*)(R + (size_t)row * DM))[t];
  const float x0 = va.x + vr.x, x1 = va.y + vr.y, x2 = va.z + vr.z, x3 = va.w + vr.w;
  float s = x0 + x1 + x2 + x3;
  float ss = x0 * x0 + x1 * x1 + x2 * x2 + x3 * x3;
#pragma unroll
  for (int o = 1; o < 64; o <<= 1) { s += __shfl_xor(s, o); ss += __shfl_xor(ss, o); }
  const float mean = s * (1.f / DM);
  const float var = ss * (1.f / DM) - mean * mean;
  const float rstd = rsqrtf(var + 1e-5f);
  const float4 vg = ((const float4*)g)[t];
  const float4 vb = ((const float4*)be)[t];
  float4 o4;
  o4.x = (x0 - mean) * rstd * vg.x + vb.x;
  o4.y = (x1 - mean) * rstd * vg.y + vb.y;
  o4.z = (x2 - mean) * rstd * vg.z + vb.z;
  o4.w = (x3 - mean) * rstd * vg.w + vb.w;
  ((float4*)(out + (size_t)row * DM))[t] = o4;
}

extern "C" void kernel_launch(void* const* d_in, const int* in_sizes, int n_in,
                              void* d_out, int out_size, void* d_ws, size_t ws_size,
                              hipStream_t stream) {
  const float* tgt  = (const float*)d_in[1];
  const float* qpos = (const float*)d_in[2];
  const float* ref  = (const float*)d_in[3];
  const float* src  = (const float*)d_in[4];
  const float* wq = (const float*)d_in[8];  const float* bq = (const float*)d_in[9];
  const float* wk = (const float*)d_in[10]; const float* bk = (const float*)d_in[11];
  const float* wv = (const float*)d_in[12]; const float* bv = (const float*)d_in[13];
  const float* wo = (const float*)d_in[14]; const float* bo = (const float*)d_in[15];
  const float* w_val = (const float*)d_in[16]; const float* b_val = (const float*)d_in[17];
  const float* w_off = (const float*)d_in[18]; const float* b_off = (const float*)d_in[19];
  const float* w_att = (const float*)d_in[20]; const float* b_att = (const float*)d_in[21];
  const float* w_out = (const float*)d_in[22]; const float* b_out = (const float*)d_in[23];
  const float* ln1g = (const float*)d_in[24]; const float* ln1b = (const float*)d_in[25];
  const float* ln2g = (const float*)d_in[26]; const float* ln2b = (const float*)d_in[27];
  const float* ln3g = (const float*)d_in[28]; const float* ln3b = (const float*)d_in[29];
  const float* w1 = (const float*)d_in[30]; const float* b1 = (const float*)d_in[31];
  const float* w2 = (const float*)d_in[32]; const float* b2 = (const float*)d_in[33];

  const size_t S = (size_t)MROW * DM;
  const size_t VAL_F = (size_t)NVAL * DM;
  float* ws = (float*)d_ws;
  float* value = ws;                 // bf16: floats [0, VAL_F/2)
  unsigned short* wp = (unsigned short*)(ws + VAL_F / 2);  // ~2 MB packed weights
  float* B0   = ws + VAL_F;
  unsigned short* Qb = (unsigned short*)(B0 + 1 * S);   // bf16
  unsigned short* Kb = (unsigned short*)(B0 + 2 * S);   // bf16
  unsigned short* Vb = (unsigned short*)(B0 + 3 * S);   // bf16
  unsigned short* Ob = (unsigned short*)(B0 + 4 * S);   // bf16
  float* tmp  = B0 + 5 * S;
  float* x1   = B0 + 0 * S;
  float* offb = B0 + 2 * S;
  float* attb = B0 + 3 * S;
  unsigned short* samp = (unsigned short*)(B0 + 4 * S); // bf16 (Ob dead by then)
  float* x2   = B0 + 6 * S;
  unsigned short* hffn = (unsigned short*)(B0 + 1 * S); // bf16, spans [1S,3S)

  const float qscale = 0.17677669529663687f;  // 1/sqrt(32)
  const dim3 blk(256);
  const dim3 gQ(DM / 64, (MROW + 63) / 64);            // (4,113)

  // ---- weight pack (one dispatch, all 10 matrices) ----
  pack_all<<<dim3(WP_TOT / 256), blk, 0, stream>>>(w_val, wq, wk, wv, wo, w_off, w_att,
                                                   w_out, w1, w2, wp);

  // ---- self-attention ----
  gemm_qkv<<<dim3(4, 113, 3), blk, 0, stream>>>(tgt, qpos, wp, bq, bk, bv,
                                                Qb, Kb, Vb, qscale);
  attn_mfma<<<dim3((LQ + 63) / 64, NH, NB), blk, 0, stream>>>(Qb, Kb, Vb, Ob);
  gemm_fused<<<gQ, blk, 0, stream>>>(Ob, wp + WP_O, bo, tmp, MROW, DM, DM, 1.f, 0, 1, 0);
  ln_kernel<<<dim3(MROW / 4), blk, 0, stream>>>(tmp, tgt, ln2g, ln2b, x1);

  // ---- deformable cross-attention ----
  value_gemm7<<<dim3(GVAL2), blk, 0, stream>>>(src, wp + WP_VAL, b_val,
                                               (unsigned short*)value, NVAL);
  gemm_offatt<<<dim3(4, 113, 2), blk, 0, stream>>>(x1, qpos, wp, b_off, b_att, offb, attb);
  sample_kernel<<<dim3((MROW * NH * 8) / 256), blk, 0, stream>>>(
      (const unsigned short*)value, ref, offb, attb, samp);
  gemm_fused<<<gQ, blk, 0, stream>>>(samp, wp + WP_OUT, b_out, tmp, MROW, DM, DM,
                                     1.f, 0, 1, 0);
  ln_kernel<<<dim3(MROW / 4), blk, 0, stream>>>(tmp, x1, ln1g, ln1b, x2);

  // ---- FFN ----
  gemm_fused<<<dim3(DFFN / 64, 113), blk, 0, stream>>>(x2, wp + WP_W1, b1, hffn, MROW,
                                                       DFFN, DM, 1.f, 1, 0, 1);
  gemm_fused<<<gQ, blk, 0, stream>>>(hffn, wp + WP_W2, b2, tmp, MROW, DM, DFFN,
                                     1.f, 0, 1, 0);
  ln_kernel<<<dim3(MROW / 4), blk, 0, stream>>>(tmp, x2, ln3g, ln3b, (float*)d_out);
}

// Round 16
// 229.427 us; speedup vs baseline: 1.1316x; 1.0074x over previous
//
#include <hip/hip_runtime.h>
#include <math.h>

#define NB 8
#define LQ 900
#define DM 256
#define NH 8
#define DH 32
#define NL 4
#define NP 4
#define DFFN 1024
#define LIN 13294
#define NVAL (NB*LIN)      // 106352 rows for value projection
#define MROW (NB*LQ)       // 7200 rows for query-side matmuls
#define GVAL2 3324         // 1662 M-strips(64) x 2 N-halves(128)

// packed-weight segment offsets (shorts)
#define WP_VAL 0
#define WP_Q   65536
#define WP_K   131072
#define WP_V   196608
#define WP_O   262144
#define WP_OFF 327680
#define WP_ATT 393216
#define WP_OUT 425984
#define WP_W1  491520
#define WP_W2  753664
#define WP_TOT 1015808     // = 3968 * 256

typedef __attribute__((ext_vector_type(8))) short bf16x8;
typedef __attribute__((ext_vector_type(4))) float f32x4;

__device__ __forceinline__ unsigned short f2bf(float x) {
  unsigned u = __float_as_uint(x);
  u += 0x7FFFu + ((u >> 16) & 1u);   // round-to-nearest-even
  return (unsigned short)(u >> 16);
}

// barrier that drains LDS ops only -- prefetched global loads stay in flight (T4)
__device__ __forceinline__ void barrier_lds_only() {
  asm volatile("s_waitcnt lgkmcnt(0)" ::: "memory");
  __builtin_amdgcn_s_barrier();
  asm volatile("" ::: "memory");
}

// ---------------- pack ALL weights: fp32 [k][n] -> bf16 tiled [kt][n][32], pre-swizzled ----------------
__global__ __launch_bounds__(256) void pack_all(
    const float* __restrict__ w_val, const float* __restrict__ wq,
    const float* __restrict__ wk, const float* __restrict__ wv,
    const float* __restrict__ wo, const float* __restrict__ w_off,
    const float* __restrict__ w_att, const float* __restrict__ w_out,
    const float* __restrict__ w1, const float* __restrict__ w2,
    unsigned short* __restrict__ Wp) {
  const int idx = blockIdx.x * 256 + threadIdx.x;
  const float* src; int r, logN;
  if (idx < WP_Q)        { src = w_val; r = idx;          logN = 8; }
  else if (idx < WP_K)   { src = wq;    r = idx - WP_Q;   logN = 8; }
  else if (idx < WP_V)   { src = wk;    r = idx - WP_K;   logN = 8; }
  else if (idx < WP_O)   { src = wv;    r = idx - WP_V;   logN = 8; }
  else if (idx < WP_OFF) { src = wo;    r = idx - WP_O;   logN = 8; }
  else if (idx < WP_ATT) { src = w_off; r = idx - WP_OFF; logN = 8; }
  else if (idx < WP_OUT) { src = w_att; r = idx - WP_ATT; logN = 7; }
  else if (idx < WP_W1)  { src = w_out; r = idx - WP_OUT; logN = 8; }
  else if (idx < WP_W2)  { src = w1;    r = idx - WP_W1;  logN = 10; }
  else                   { src = w2;    r = idx - WP_W2;  logN = 8; }
  const int N = 1 << logN;
  const int e = r & 7, cs = (r >> 3) & 3;
  const int n = (r >> 5) & (N - 1);
  const int kt = r >> (5 + logN);
  const int c = cs ^ ((n >> 1) & 3);
  const int k = kt * 32 + c * 8 + e;
  Wp[idx] = f2bf(src[(size_t)k * N + n]);
}

// ---------------- value GEMM v8: v4 structure, LDS-only barrier in K-loop ----------------
__global__ __launch_bounds__(256) void value_gemm8(const float* __restrict__ A,
                                                   const unsigned short* __restrict__ Wp,
                                                   const float* __restrict__ bias,
                                                   unsigned short* __restrict__ C,
                                                   int M) {
  __shared__ char lds[24576];
  short* As = (short*)lds;             // 2 x 2048 shorts (64x32, chunk-swizzled)
  short* Bs = (short*)(lds + 8192);    // 2 x 4096 shorts (128x32, linear pre-swizzled)
  const int tid = threadIdx.x;
  const int lane = tid & 63, w = tid >> 6;
  const int wr = w >> 1, wc = w & 1;
  const int l15 = lane & 15, lc = lane >> 4;
  const int nwg = gridDim.x;
  const int qq = nwg >> 3, rr = nwg & 7;
  const int xcd = blockIdx.x & 7, pos = blockIdx.x >> 3;
  const int wgid = (xcd < rr ? xcd * (qq + 1) : rr * (qq + 1) + (xcd - rr) * qq) + pos;
  const int m0 = (wgid >> 1) * 64, n0 = (wgid & 1) * 128;
  const int ar = tid >> 2, ac = tid & 3;
  const int arow = min(m0 + ar, M - 1);
  f32x4 acc[2][4] = {};
  float4 pa0, pa1; uint4 pb0, pb1;
  {
    const float* ap_ = A + (size_t)arow * 256 + ac * 8;
    pa0 = ((const float4*)ap_)[0]; pa1 = ((const float4*)ap_)[1];
    const unsigned short* bp_ = Wp + ((size_t)n0) * 32 + tid * 16;
    pb0 = ((const uint4*)bp_)[0]; pb1 = ((const uint4*)bp_)[1];
  }
#pragma unroll
  for (int kt = 0; kt < 256; kt += 32) {
    short* Ac = As + ((kt >> 5) & 1) * 2048;
    short* Bc = Bs + ((kt >> 5) & 1) * 4096;
    {
      bf16x8 av;
      av[0] = (short)f2bf(pa0.x); av[1] = (short)f2bf(pa0.y);
      av[2] = (short)f2bf(pa0.z); av[3] = (short)f2bf(pa0.w);
      av[4] = (short)f2bf(pa1.x); av[5] = (short)f2bf(pa1.y);
      av[6] = (short)f2bf(pa1.z); av[7] = (short)f2bf(pa1.w);
      *(bf16x8*)&Ac[ar * 32 + ((ac ^ ((ar >> 1) & 3)) << 3)] = av;
      *(uint4*)&Bc[tid * 16] = pb0;
      *(uint4*)&Bc[tid * 16 + 8] = pb1;
    }
    barrier_lds_only();   // LDS staged; prefetched globals stay in flight
    if (kt + 32 < 256) {  // prefetch next tile; latency spans the NEXT barrier too
      const float* ap_ = A + (size_t)arow * 256 + kt + 32 + ac * 8;
      pa0 = ((const float4*)ap_)[0]; pa1 = ((const float4*)ap_)[1];
      const unsigned short* bp_ = Wp + ((size_t)(((kt >> 5) + 1) * 256 + n0)) * 32 + tid * 16;
      pb0 = ((const uint4*)bp_)[0]; pb1 = ((const uint4*)bp_)[1];
    }
    bf16x8 af[2], bq[4];
#pragma unroll
    for (int i = 0; i < 2; i++) {
      const int row = wr * 32 + i * 16 + l15;
      af[i] = *(const bf16x8*)&Ac[row * 32 + ((lc ^ ((row >> 1) & 3)) << 3)];
    }
#pragma unroll
    for (int q = 0; q < 4; q++) {
      const int col = wc * 64 + q * 16 + l15;
      bq[q] = *(const bf16x8*)&Bc[col * 32 + ((lc ^ ((col >> 1) & 3)) << 3)];
    }
#pragma unroll
    for (int i = 0; i < 2; i++)
#pragma unroll
      for (int q = 0; q < 4; q++)
        acc[i][q] = __builtin_amdgcn_mfma_f32_16x16x32_bf16(af[i], bq[q], acc[i][q], 0, 0, 0);
  }
  // ---- epilogue: bias + bf16 via per-wave strip (full barrier fine, once) ----
  __syncthreads();
  short* strip = (short*)lds + w * 2176;   // 32 rows x 68 shorts
  float bv[4];
#pragma unroll
  for (int q = 0; q < 4; q++) bv[q] = bias[n0 + wc * 64 + q * 16 + l15];
#pragma unroll
  for (int i = 0; i < 2; i++)
#pragma unroll
    for (int q = 0; q < 4; q++)
#pragma unroll
      for (int r = 0; r < 4; r++)
        strip[(i * 16 + lc * 4 + r) * 68 + q * 16 + l15] = (short)f2bf(acc[i][q][r] + bv[q]);
  __syncthreads();
#pragma unroll
  for (int p = 0; p < 4; p++) {
    const int row = p * 8 + (lane >> 3), c8 = lane & 7;
    const bf16x8 v = *(const bf16x8*)&strip[row * 68 + c8 * 8];
    const int grow = m0 + wr * 32 + row;
    if (grow < M)
      *(bf16x8*)(C + (size_t)grow * 256 + n0 + wc * 64 + c8 * 8) = v;
  }
}

// ---------------- shared GEMM body: 64x64 tile, packed B, pipelined (1 barrier/iter) ----------------
__device__ __forceinline__ void gemm_body(const void* Aptr, const float* A2,
                                          const unsigned short* __restrict__ Wp,
                                          const float* __restrict__ bias, void* Cptr,
                                          int M, int Nn, int K, float scale, int relu,
                                          int a_bf16, int out_bf16, int m0, int n0,
                                          short* As, short* Bs) {
  const int tid = threadIdx.x;
  const int lane = tid & 63, w = tid >> 6;
  const int wr = w >> 1, wc = w & 1;
  const int ar = tid >> 2, ac = tid & 3;
  const int l15 = lane & 15, lc = lane >> 4;
  const int arow = min(m0 + ar, M - 1);
  f32x4 acc[2][2] = {};
  float4 pa0, pa1, pc0, pc1; bf16x8 pav; uint4 pb;
  {
    if (a_bf16) {
      pav = *(const bf16x8*)((const unsigned short*)Aptr + (size_t)arow * K + ac * 8);
    } else {
      const float* ap_ = (const float*)Aptr + (size_t)arow * K + ac * 8;
      pa0 = ((const float4*)ap_)[0]; pa1 = ((const float4*)ap_)[1];
      if (A2) {
        const float* cp_ = A2 + (size_t)arow * K + ac * 8;
        pc0 = ((const float4*)cp_)[0]; pc1 = ((const float4*)cp_)[1];
      }
    }
    pb = *(const uint4*)(Wp + ((size_t)n0) * 32 + tid * 8);
  }
  for (int kt = 0; kt < K; kt += 32) {
    short* Ac = As + ((kt >> 5) & 1) * 2048;
    short* Bc = Bs + ((kt >> 5) & 1) * 2048;
    {
      bf16x8 av;
      if (a_bf16) {
        av = pav;
      } else {
        float4 a0 = pa0, a1 = pa1;
        if (A2) {
          a0.x += pc0.x; a0.y += pc0.y; a0.z += pc0.z; a0.w += pc0.w;
          a1.x += pc1.x; a1.y += pc1.y; a1.z += pc1.z; a1.w += pc1.w;
        }
        av[0] = (short)f2bf(a0.x); av[1] = (short)f2bf(a0.y);
        av[2] = (short)f2bf(a0.z); av[3] = (short)f2bf(a0.w);
        av[4] = (short)f2bf(a1.x); av[5] = (short)f2bf(a1.y);
        av[6] = (short)f2bf(a1.z); av[7] = (short)f2bf(a1.w);
      }
      *(bf16x8*)&Ac[ar * 32 + ((ac ^ ((ar >> 1) & 3)) << 3)] = av;
      *(uint4*)&Bc[tid * 8] = pb;
    }
    barrier_lds_only();
    if (kt + 32 < K) {   // prefetch next tile into regs
      if (a_bf16) {
        pav = *(const bf16x8*)((const unsigned short*)Aptr + (size_t)arow * K + kt + 32 + ac * 8);
      } else {
        const float* ap_ = (const float*)Aptr + (size_t)arow * K + kt + 32 + ac * 8;
        pa0 = ((const float4*)ap_)[0]; pa1 = ((const float4*)ap_)[1];
        if (A2) {
          const float* cp_ = A2 + (size_t)arow * K + kt + 32 + ac * 8;
          pc0 = ((const float4*)cp_)[0]; pc1 = ((const float4*)cp_)[1];
        }
      }
      pb = *(const uint4*)(Wp + ((size_t)(((kt >> 5) + 1) * Nn + n0)) * 32 + tid * 8);
    }
    bf16x8 af[2], bf[2];
#pragma unroll
    for (int i = 0; i < 2; i++) {
      const int row = wr * 32 + i * 16 + l15;
      af[i] = *(const bf16x8*)&Ac[row * 32 + ((lc ^ ((row >> 1) & 3)) << 3)];
      const int col = wc * 32 + i * 16 + l15;
      bf[i] = *(const bf16x8*)&Bc[col * 32 + ((lc ^ ((col >> 1) & 3)) << 3)];
    }
#pragma unroll
    for (int i = 0; i < 2; i++)
#pragma unroll
      for (int j = 0; j < 2; j++)
        acc[i][j] = __builtin_amdgcn_mfma_f32_16x16x32_bf16(af[i], bf[j], acc[i][j], 0, 0, 0);
  }
#pragma unroll
  for (int i = 0; i < 2; i++) {
    const int row0 = m0 + wr * 32 + i * 16 + lc * 4;
#pragma unroll
    for (int j = 0; j < 2; j++) {
      const int col = n0 + wc * 32 + j * 16 + l15;
      const float bv = bias[col];
#pragma unroll
      for (int r = 0; r < 4; r++) {
        const int row = row0 + r;
        if (row < M) {
          float v = (acc[i][j][r] + bv) * scale;
          if (relu) v = fmaxf(v, 0.f);
          if (out_bf16)
            ((unsigned short*)Cptr)[(size_t)row * Nn + col] = f2bf(v);
          else
            ((float*)Cptr)[(size_t)row * Nn + col] = v;
        }
      }
    }
  }
}

// ---------------- fused QKV projection: z selects Q/K/V; add(tgt,qpos) fused; bf16 out ----------------
__global__ __launch_bounds__(256) void gemm_qkv(const float* __restrict__ tgt,
                                                const float* __restrict__ qpos,
                                                const unsigned short* __restrict__ Wp,
                                                const float* __restrict__ bq_,
                                                const float* __restrict__ bk_,
                                                const float* __restrict__ bv_,
                                                unsigned short* Qb, unsigned short* Kb,
                                                unsigned short* Vb, float qscale) {
  __shared__ short As[2 * 2048];
  __shared__ short Bs[2 * 2048];
  const int z = blockIdx.z;
  const unsigned short* W = Wp + (z == 0 ? WP_Q : z == 1 ? WP_K : WP_V);
  const float* bias = (z == 0) ? bq_ : (z == 1) ? bk_ : bv_;
  unsigned short* C = (z == 0) ? Qb : (z == 1) ? Kb : Vb;
  const float* A2 = (z == 2) ? nullptr : qpos;
  gemm_body(tgt, A2, W, bias, C, MROW, DM, DM, (z == 0) ? qscale : 1.f, 0, 0, 1,
            blockIdx.y * 64, blockIdx.x * 64, As, Bs);
}

// ---------------- fused offset+attention-logit projection: add(x1,qpos) fused ----------------
__global__ __launch_bounds__(256) void gemm_offatt(const float* __restrict__ x1,
                                                   const float* __restrict__ qpos,
                                                   const unsigned short* __restrict__ Wp,
                                                   const float* __restrict__ b_off,
                                                   const float* __restrict__ b_att,
                                                   float* offb, float* attb) {
  const int z = blockIdx.z;
  if (z == 1 && blockIdx.x >= 2) return;
  __shared__ short As[2 * 2048];
  __shared__ short Bs[2 * 2048];
  const unsigned short* W = Wp + (z ? WP_ATT : WP_OFF);
  const float* bias = z ? b_att : b_off;
  float* C = z ? attb : offb;
  const int Nn = z ? 128 : 256;
  gemm_body(x1, qpos, W, bias, C, MROW, Nn, DM, 1.f, 0, 0, 0,
            blockIdx.y * 64, blockIdx.x * 64, As, Bs);
}

// ---------------- generic GEMM dispatch (packed B) ----------------
__global__ __launch_bounds__(256) void gemm_fused(const void* A, const unsigned short* Wp,
                                                  const float* bias, void* C, int M, int Nn,
                                                  int K, float scale, int relu, int a_bf16,
                                                  int out_bf16) {
  __shared__ short As[2 * 2048];
  __shared__ short Bs[2 * 2048];
  gemm_body(A, nullptr, Wp, bias, C, M, Nn, K, scale, relu, a_bf16, out_bf16,
            blockIdx.y * 64, blockIdx.x * 64, As, Bs);
}

// ---------------- MFMA flash attention (bf16 in/out, next-tile reg prefetch) ----------------
__global__ __launch_bounds__(256) void attn_mfma(const unsigned short* __restrict__ Qg,
                                                 const unsigned short* __restrict__ Kg,
                                                 const unsigned short* __restrict__ Vg,
                                                 unsigned short* __restrict__ O) {
  __shared__ short Ks[2048];
  __shared__ short Vt[2048];
  __shared__ short Pl[4096];
  const int tid = threadIdx.x;
  const int lane = tid & 63, w = tid >> 6;
  const int l15 = lane & 15, lc = lane >> 4;
  const int h = blockIdx.y, b = blockIdx.z;
  const int q0 = blockIdx.x * 64;
  char* KsB = (char*)Ks; char* VtB = (char*)Vt; char* PlB = (char*)Pl + w * 2048;

  bf16x8 qa;
  {
    const int qrow = min(q0 + w * 16 + l15, LQ - 1);
    qa = *(const bf16x8*)(Qg + ((size_t)(b * LQ + qrow)) * DM + h * DH + lc * 8);
  }
  f32x4 o0 = {0.f, 0.f, 0.f, 0.f}, o1 = {0.f, 0.f, 0.f, 0.f};
  float mrow[4], lrow[4];
#pragma unroll
  for (int r = 0; r < 4; r++) { mrow[r] = -1e30f; lrow[r] = 0.f; }
  const int skey = tid >> 2, sq = tid & 3;

  // preload tile 0
  bf16x8 kb, vv;
  {
    const int kr = min(skey, LQ - 1);
    kb = *(const bf16x8*)(Kg + ((size_t)(b * LQ + kr)) * DM + h * DH + sq * 8);
    vv = *(const bf16x8*)(Vg + ((size_t)(b * LQ + kr)) * DM + h * DH + sq * 8);
  }
  for (int kt = 0; kt < LQ; kt += 64) {
    __syncthreads();   // prev tile's LDS reads done
    {
      *(bf16x8*)(KsB + ((skey * 64 + sq * 16) ^ ((skey & 7) << 4))) = kb;
#pragma unroll
      for (int j = 0; j < 8; j++) {
        const int dh = sq * 8 + j;
        const int qz = ((dh & 7) ^ (((dh >> 3) & 3) << 1)) << 4;
        *(short*)(VtB + ((dh * 128 + skey * 2) ^ qz)) = (short)vv[j];
      }
    }
    __syncthreads();   // staging visible
    if (kt + 64 < LQ) {   // prefetch next K/V tile; hides under S/softmax/PV below
      const int kr = min(kt + 64 + skey, LQ - 1);
      kb = *(const bf16x8*)(Kg + ((size_t)(b * LQ + kr)) * DM + h * DH + sq * 8);
      vv = *(const bf16x8*)(Vg + ((size_t)(b * LQ + kr)) * DM + h * DH + sq * 8);
    }
    f32x4 s[4];
#pragma unroll
    for (int cb = 0; cb < 4; cb++) {
      const int key = cb * 16 + l15;
      const bf16x8 kf = *(const bf16x8*)(KsB + ((key * 64 + lc * 16) ^ ((key & 7) << 4)));
      const f32x4 z = {0.f, 0.f, 0.f, 0.f};
      s[cb] = __builtin_amdgcn_mfma_f32_16x16x32_bf16(qa, kf, z, 0, 0, 0);
    }
#pragma unroll
    for (int cb = 0; cb < 4; cb++)
      if (kt + cb * 16 + l15 >= LQ) {
        s[cb][0] = -1e30f; s[cb][1] = -1e30f; s[cb][2] = -1e30f; s[cb][3] = -1e30f;
      }
    float tm[4], fs[4], ps[4];
#pragma unroll
    for (int r = 0; r < 4; r++)
      tm[r] = fmaxf(fmaxf(s[0][r], s[1][r]), fmaxf(s[2][r], s[3][r]));
#pragma unroll
    for (int msk = 1; msk <= 8; msk <<= 1)
#pragma unroll
      for (int r = 0; r < 4; r++) tm[r] = fmaxf(tm[r], __shfl_xor(tm[r], msk));
#pragma unroll
    for (int r = 0; r < 4; r++) {
      const float nm = fmaxf(mrow[r], tm[r]);
      fs[r] = __expf(mrow[r] - nm);
      mrow[r] = nm;
    }
#pragma unroll
    for (int cb = 0; cb < 4; cb++)
#pragma unroll
      for (int r = 0; r < 4; r++) s[cb][r] = __expf(s[cb][r] - mrow[r]);
#pragma unroll
    for (int r = 0; r < 4; r++) ps[r] = (s[0][r] + s[1][r]) + (s[2][r] + s[3][r]);
#pragma unroll
    for (int msk = 1; msk <= 8; msk <<= 1)
#pragma unroll
      for (int r = 0; r < 4; r++) ps[r] += __shfl_xor(ps[r], msk);
#pragma unroll
    for (int r = 0; r < 4; r++) {
      lrow[r] = lrow[r] * fs[r] + ps[r];
      o0[r] *= fs[r]; o1[r] *= fs[r];
    }
#pragma unroll
    for (int cb = 0; cb < 4; cb++)
#pragma unroll
      for (int r = 0; r < 4; r++) {
        const int row = lc * 4 + r, col = cb * 16 + l15;
        *(short*)(PlB + ((row * 128 + col * 2) ^ ((row & 7) << 4))) = (short)f2bf(s[cb][r]);
      }
#pragma unroll
    for (int ks2 = 0; ks2 < 2; ks2++) {
      const int koff2 = (ks2 * 32 + lc * 8) * 2;
      const bf16x8 pa = *(const bf16x8*)(PlB + ((l15 * 128 + koff2) ^ ((l15 & 7) << 4)));
      {
        const int dh = l15;
        const int qz = ((dh & 7) ^ (((dh >> 3) & 3) << 1)) << 4;
        const bf16x8 vf = *(const bf16x8*)(VtB + ((dh * 128 + koff2) ^ qz));
        o0 = __builtin_amdgcn_mfma_f32_16x16x32_bf16(pa, vf, o0, 0, 0, 0);
      }
      {
        const int dh = 16 + l15;
        const int qz = ((dh & 7) ^ (((dh >> 3) & 3) << 1)) << 4;
        const bf16x8 vf = *(const bf16x8*)(VtB + ((dh * 128 + koff2) ^ qz));
        o1 = __builtin_amdgcn_mfma_f32_16x16x32_bf16(pa, vf, o1, 0, 0, 0);
      }
    }
  }
#pragma unroll
  for (int r = 0; r < 4; r++) {
    const int qrow = q0 + w * 16 + lc * 4 + r;
    if (qrow < LQ) {
      const float inv = 1.f / lrow[r];
      unsigned short* op = O + ((size_t)(b * LQ + qrow)) * DM + h * DH;
      op[l15] = f2bf(o0[r] * inv);
      op[16 + l15] = f2bf(o1[r] * inv);
    }
  }
}

// ---------------- MS-deform sampling: 8 threads per (b,q,h), 4 channels each; bf16 out ----------------
__global__ __launch_bounds__(256) void sample_kernel(const unsigned short* __restrict__ value,
                                                     const float* __restrict__ ref,
                                                     const float* __restrict__ off,
                                                     const float* __restrict__ att,
                                                     unsigned short* __restrict__ out) {
  const int t = blockIdx.x * 256 + threadIdx.x;   // < NB*LQ*NH*8 = 460800
  const int d4 = t & 7;
  const int h = (t >> 3) & 7;
  const int qb = t >> 6;                           // b*LQ + q
  const int b = qb / LQ;
  const int HLs[4] = {100, 50, 25, 13};
  const int STs[4] = {0, 10000, 12500, 13125};
  const float* rp = ref + (size_t)qb * (NL * 2);
  const float* op = off + (size_t)qb * DM + h * (NL * NP * 2);
  const float* ap = att + (size_t)qb * (NH * NL * NP) + h * (NL * NP);
  const unsigned short* vb = value + (size_t)b * LIN * DM + h * DH + d4 * 4;

  float aw[16];
#pragma unroll
  for (int i = 0; i < 4; i++) {
    const float4 a4 = ((const float4*)ap)[i];
    aw[4 * i] = a4.x; aw[4 * i + 1] = a4.y; aw[4 * i + 2] = a4.z; aw[4 * i + 3] = a4.w;
  }
  float am = aw[0];
#pragma unroll
  for (int i = 1; i < 16; i++) am = fmaxf(am, aw[i]);
  float asum = 0.f;
#pragma unroll
  for (int i = 0; i < 16; i++) { aw[i] = __expf(aw[i] - am); asum += aw[i]; }
  const float ainv = 1.f / asum;

  float acc[4] = {};
#pragma unroll
  for (int l = 0; l < NL; l++) {
    const int Hl = HLs[l], Wl = HLs[l], st = STs[l];
    const float rx = rp[l * 2], ry = rp[l * 2 + 1];
#pragma unroll
    for (int p = 0; p < NP; p++) {
      const float2 o2 = ((const float2*)op)[l * NP + p];
      const float a = aw[l * NP + p] * ainv;
      const float locx = rx + o2.x / (float)Wl;
      const float locy = ry + o2.y / (float)Hl;
      const float x = locx * (float)Wl - 0.5f;
      const float y = locy * (float)Hl - 0.5f;
      const float xf = floorf(x), yf = floorf(y);
      const float fx = x - xf, fy = y - yf;
      const int x0 = (int)xf, y0 = (int)yf;
      const int x1 = x0 + 1, y1 = y0 + 1;
      const float vx0 = (x0 >= 0 && x0 < Wl) ? 1.f : 0.f;
      const float vx1 = (x1 >= 0 && x1 < Wl) ? 1.f : 0.f;
      const float vy0 = (y0 >= 0 && y0 < Hl) ? 1.f : 0.f;
      const float vy1 = (y1 >= 0 && y1 < Hl) ? 1.f : 0.f;
      const int cx0 = min(max(x0, 0), Wl - 1), cx1 = min(max(x1, 0), Wl - 1);
      const int cy0 = min(max(y0, 0), Hl - 1), cy1 = min(max(y1, 0), Hl - 1);
      const float w00 = a * (1.f - fx) * (1.f - fy) * vx0 * vy0;
      const float w10 = a * fx * (1.f - fy) * vx1 * vy0;
      const float w01 = a * (1.f - fx) * fy * vx0 * vy1;
      const float w11 = a * fx * fy * vx1 * vy1;
      const unsigned short* r0 = vb + (size_t)(st + cy0 * Wl) * DM;
      const unsigned short* r1 = vb + (size_t)(st + cy1 * Wl) * DM;
      const uint2 g00 = *(const uint2*)(r0 + (size_t)cx0 * DM);
      const uint2 g10 = *(const uint2*)(r0 + (size_t)cx1 * DM);
      const uint2 g01 = *(const uint2*)(r1 + (size_t)cx0 * DM);
      const uint2 g11 = *(const uint2*)(r1 + (size_t)cx1 * DM);
      const unsigned u00[2] = {g00.x, g00.y};
      const unsigned u10[2] = {g10.x, g10.y};
      const unsigned u01[2] = {g01.x, g01.y};
      const unsigned u11[2] = {g11.x, g11.y};
#pragma unroll
      for (int i = 0; i < 2; i++) {
        acc[2 * i]     += w00 * __uint_as_float(u00[i] << 16) + w10 * __uint_as_float(u10[i] << 16)
                        + w01 * __uint_as_float(u01[i] << 16) + w11 * __uint_as_float(u11[i] << 16);
        acc[2 * i + 1] += w00 * __uint_as_float(u00[i] & 0xFFFF0000u) + w10 * __uint_as_float(u10[i] & 0xFFFF0000u)
                        + w01 * __uint_as_float(u01[i] & 0xFFFF0000u) + w11 * __uint_as_float(u11[i] & 0xFFFF0000u);
      }
    }
  }
  uint2 ov;
  ov.x = (unsigned)f2bf(acc[0]) | ((unsigned)f2bf(acc[1]) << 16);
  ov.y = (unsigned)f2bf(acc[2]) | ((unsigned)f2bf(acc[3]) << 16);
  *(uint2*)(out + (size_t)t * 4) = ov;
}

// ---------------- fused residual-add + LayerNorm, 4 rows per block (1 wave/row) ----------------
__global__ __launch_bounds__(256) void ln_kernel(const float* __restrict__ A,
                                                 const float* __restrict__ R,
                                                 const float* __restrict__ g,
                                                 const float* __restrict__ be,
                                                 float* __restrict__ out) {
  const int row = blockIdx.x * 4 + (threadIdx.x >> 6);
  const int t = threadIdx.x & 63;
  const float4 va = ((const float4*)(A + (size_t)row * DM))[t];
  const float4 vr = ((const float4*)(R + (size_t)row * DM))[t];
  const float x0 = va.x + vr.x, x1 = va.y + vr.y, x2 = va.z + vr.z, x3 = va.w + vr.w;
  float s = x0 + x1 + x2 + x3;
  float ss = x0 * x0 + x1 * x1 + x2 * x2 + x3 * x3;
#pragma unroll
  for (int o = 1; o < 64; o <<= 1) { s += __shfl_xor(s, o); ss += __shfl_xor(ss, o); }
  const float mean = s * (1.f / DM);
  const float var = ss * (1.f / DM) - mean * mean;
  const float rstd = rsqrtf(var + 1e-5f);
  const float4 vg = ((const float4*)g)[t];
  const float4 vb = ((const float4*)be)[t];
  float4 o4;
  o4.x = (x0 - mean) * rstd * vg.x + vb.x;
  o4.y = (x1 - mean) * rstd * vg.y + vb.y;
  o4.z = (x2 - mean) * rstd * vg.z + vb.z;
  o4.w = (x3 - mean) * rstd * vg.w + vb.w;
  ((float4*)(out + (size_t)row * DM))[t] = o4;
}

extern "C" void kernel_launch(void* const* d_in, const int* in_sizes, int n_in,
                              void* d_out, int out_size, void* d_ws, size_t ws_size,
                              hipStream_t stream) {
  const float* tgt  = (const float*)d_in[1];
  const float* qpos = (const float*)d_in[2];
  const float* ref  = (const float*)d_in[3];
  const float* src  = (const float*)d_in[4];
  const float* wq = (const float*)d_in[8];  const float* bq = (const float*)d_in[9];
  const float* wk = (const float*)d_in[10]; const float* bk = (const float*)d_in[11];
  const float* wv = (const float*)d_in[12]; const float* bv = (const float*)d_in[13];
  const float* wo = (const float*)d_in[14]; const float* bo = (const float*)d_in[15];
  const float* w_val = (const float*)d_in[16]; const float* b_val = (const float*)d_in[17];
  const float* w_off = (const float*)d_in[18]; const float* b_off = (const float*)d_in[19];
  const float* w_att = (const float*)d_in[20]; const float* b_att = (const float*)d_in[21];
  const float* w_out = (const float*)d_in[22]; const float* b_out = (const float*)d_in[23];
  const float* ln1g = (const float*)d_in[24]; const float* ln1b = (const float*)d_in[25];
  const float* ln2g = (const float*)d_in[26]; const float* ln2b = (const float*)d_in[27];
  const float* ln3g = (const float*)d_in[28]; const float* ln3b = (const float*)d_in[29];
  const float* w1 = (const float*)d_in[30]; const float* b1 = (const float*)d_in[31];
  const float* w2 = (const float*)d_in[32]; const float* b2 = (const float*)d_in[33];

  const size_t S = (size_t)MROW * DM;
  const size_t VAL_F = (size_t)NVAL * DM;
  float* ws = (float*)d_ws;
  float* value = ws;                 // bf16: floats [0, VAL_F/2)
  unsigned short* wp = (unsigned short*)(ws + VAL_F / 2);  // ~2 MB packed weights
  float* B0   = ws + VAL_F;
  unsigned short* Qb = (unsigned short*)(B0 + 1 * S);   // bf16
  unsigned short* Kb = (unsigned short*)(B0 + 2 * S);   // bf16
  unsigned short* Vb = (unsigned short*)(B0 + 3 * S);   // bf16
  unsigned short* Ob = (unsigned short*)(B0 + 4 * S);   // bf16
  float* tmp  = B0 + 5 * S;
  float* x1   = B0 + 0 * S;
  float* offb = B0 + 2 * S;
  float* attb = B0 + 3 * S;
  unsigned short* samp = (unsigned short*)(B0 + 4 * S); // bf16 (Ob dead by then)
  float* x2   = B0 + 6 * S;
  unsigned short* hffn = (unsigned short*)(B0 + 1 * S); // bf16, spans [1S,3S)

  const float qscale = 0.17677669529663687f;  // 1/sqrt(32)
  const dim3 blk(256);
  const dim3 gQ(DM / 64, (MROW + 63) / 64);            // (4,113)

  // ---- weight pack (one dispatch, all 10 matrices) ----
  pack_all<<<dim3(WP_TOT / 256), blk, 0, stream>>>(w_val, wq, wk, wv, wo, w_off, w_att,
                                                   w_out, w1, w2, wp);

  // ---- self-attention ----
  gemm_qkv<<<dim3(4, 113, 3), blk, 0, stream>>>(tgt, qpos, wp, bq, bk, bv,
                                                Qb, Kb, Vb, qscale);
  attn_mfma<<<dim3((LQ + 63) / 64, NH, NB), blk, 0, stream>>>(Qb, Kb, Vb, Ob);
  gemm_fused<<<gQ, blk, 0, stream>>>(Ob, wp + WP_O, bo, tmp, MROW, DM, DM, 1.f, 0, 1, 0);
  ln_kernel<<<dim3(MROW / 4), blk, 0, stream>>>(tmp, tgt, ln2g, ln2b, x1);

  // ---- deformable cross-attention ----
  value_gemm8<<<dim3(GVAL2), blk, 0, stream>>>(src, wp + WP_VAL, b_val,
                                               (unsigned short*)value, NVAL);
  gemm_offatt<<<dim3(4, 113, 2), blk, 0, stream>>>(x1, qpos, wp, b_off, b_att, offb, attb);
  sample_kernel<<<dim3((MROW * NH * 8) / 256), blk, 0, stream>>>(
      (const unsigned short*)value, ref, offb, attb, samp);
  gemm_fused<<<gQ, blk, 0, stream>>>(samp, wp + WP_OUT, b_out, tmp, MROW, DM, DM,
                                     1.f, 0, 1, 0);
  ln_kernel<<<dim3(MROW / 4), blk, 0, stream>>>(tmp, x1, ln1g, ln1b, x2);

  // ---- FFN ----
  gemm_fused<<<dim3(DFFN / 64, 113), blk, 0, stream>>>(x2, wp + WP_W1, b1, hffn, MROW,
                                                       DFFN, DM, 1.f, 1, 0, 1);
  gemm_fused<<<gQ, blk, 0, stream>>>(hffn, wp + WP_W2, b2, tmp, MROW, DM, DFFN,
                                     1.f, 0, 1, 0);
  ln_kernel<<<dim3(MROW / 4), blk, 0, stream>>>(tmp, x2, ln3g, ln3b, (float*)d_out);
}

// Round 17
// 225.216 us; speedup vs baseline: 1.1528x; 1.0187x over previous
//
#include <hip/hip_runtime.h>
#include <math.h>

#define NB 8
#define LQ 900
#define DM 256
#define NH 8
#define DH 32
#define NL 4
#define NP 4
#define DFFN 1024
#define LIN 13294
#define NVAL (NB*LIN)      // 106352 rows for value projection
#define MROW (NB*LQ)       // 7200 rows for query-side matmuls
#define GVAL2 3324         // 1662 M-strips(64) x 2 N-halves(128)

// packed-weight segment offsets (shorts)
#define WP_VAL 0
#define WP_Q   65536
#define WP_K   131072
#define WP_V   196608
#define WP_O   262144
#define WP_OFF 327680
#define WP_ATT 393216
#define WP_OUT 425984
#define WP_W1  491520
#define WP_W2  753664
#define WP_TOT 1015808     // = 3968 * 256

typedef __attribute__((ext_vector_type(8))) short bf16x8;
typedef __attribute__((ext_vector_type(4))) float f32x4;

__device__ __forceinline__ unsigned short f2bf(float x) {
  unsigned u = __float_as_uint(x);
  u += 0x7FFFu + ((u >> 16) & 1u);   // round-to-nearest-even
  return (unsigned short)(u >> 16);
}

// barrier that drains LDS ops only -- prefetched global loads stay in flight (T4)
__device__ __forceinline__ void barrier_lds_only() {
  asm volatile("s_waitcnt lgkmcnt(0)" ::: "memory");
  __builtin_amdgcn_s_barrier();
  asm volatile("" ::: "memory");
}

// ---------------- pack ALL weights: fp32 [k][n] -> bf16 tiled [kt][n][32], pre-swizzled ----------------
__global__ __launch_bounds__(256) void pack_all(
    const float* __restrict__ w_val, const float* __restrict__ wq,
    const float* __restrict__ wk, const float* __restrict__ wv,
    const float* __restrict__ wo, const float* __restrict__ w_off,
    const float* __restrict__ w_att, const float* __restrict__ w_out,
    const float* __restrict__ w1, const float* __restrict__ w2,
    unsigned short* __restrict__ Wp) {
  const int idx = blockIdx.x * 256 + threadIdx.x;
  const float* src; int r, logN;
  if (idx < WP_Q)        { src = w_val; r = idx;          logN = 8; }
  else if (idx < WP_K)   { src = wq;    r = idx - WP_Q;   logN = 8; }
  else if (idx < WP_V)   { src = wk;    r = idx - WP_K;   logN = 8; }
  else if (idx < WP_O)   { src = wv;    r = idx - WP_V;   logN = 8; }
  else if (idx < WP_OFF) { src = wo;    r = idx - WP_O;   logN = 8; }
  else if (idx < WP_ATT) { src = w_off; r = idx - WP_OFF; logN = 8; }
  else if (idx < WP_OUT) { src = w_att; r = idx - WP_ATT; logN = 7; }
  else if (idx < WP_W1)  { src = w_out; r = idx - WP_OUT; logN = 8; }
  else if (idx < WP_W2)  { src = w1;    r = idx - WP_W1;  logN = 10; }
  else                   { src = w2;    r = idx - WP_W2;  logN = 8; }
  const int N = 1 << logN;
  const int e = r & 7, cs = (r >> 3) & 3;
  const int n = (r >> 5) & (N - 1);
  const int kt = r >> (5 + logN);
  const int c = cs ^ ((n >> 1) & 3);
  const int k = kt * 32 + c * 8 + e;
  Wp[idx] = f2bf(src[(size_t)k * N + n]);
}

// ---------------- value GEMM v9: v8 + depth-2 register pipeline ----------------
__global__ __launch_bounds__(256) void value_gemm9(const float* __restrict__ A,
                                                   const unsigned short* __restrict__ Wp,
                                                   const float* __restrict__ bias,
                                                   unsigned short* __restrict__ C,
                                                   int M) {
  __shared__ char lds[24576];
  short* As = (short*)lds;             // 2 x 2048 shorts (64x32, chunk-swizzled)
  short* Bs = (short*)(lds + 8192);    // 2 x 4096 shorts (128x32, linear pre-swizzled)
  const int tid = threadIdx.x;
  const int lane = tid & 63, w = tid >> 6;
  const int wr = w >> 1, wc = w & 1;
  const int l15 = lane & 15, lc = lane >> 4;
  const int nwg = gridDim.x;
  const int qq = nwg >> 3, rr = nwg & 7;
  const int xcd = blockIdx.x & 7, pos = blockIdx.x >> 3;
  const int wgid = (xcd < rr ? xcd * (qq + 1) : rr * (qq + 1) + (xcd - rr) * qq) + pos;
  const int m0 = (wgid >> 1) * 64, n0 = (wgid & 1) * 128;
  const int ar = tid >> 2, ac = tid & 3;
  const int arow = min(m0 + ar, M - 1);
  f32x4 acc[2][4] = {};
  const float* abase = A + (size_t)arow * 256 + ac * 8;
  // depth-2 register pipeline: set A holds tile kt (even), set B tile kt (odd)
  float4 aA0, aA1, aB0, aB1; uint4 bA0, bA1, bB0, bB1;
  {
    aA0 = ((const float4*)abase)[0]; aA1 = ((const float4*)abase)[1];
    const unsigned short* bp0 = Wp + ((size_t)n0) * 32 + tid * 16;
    bA0 = ((const uint4*)bp0)[0]; bA1 = ((const uint4*)bp0)[1];
    aB0 = ((const float4*)(abase + 32))[0]; aB1 = ((const float4*)(abase + 32))[1];
    const unsigned short* bp1 = Wp + ((size_t)(256 + n0)) * 32 + tid * 16;
    bB0 = ((const uint4*)bp1)[0]; bB1 = ((const uint4*)bp1)[1];
  }
#pragma unroll
  for (int kt = 0; kt < 8; kt++) {
    short* Ac = As + (kt & 1) * 2048;
    short* Bc = Bs + (kt & 1) * 4096;
    const float4 sa0 = (kt & 1) ? aB0 : aA0;
    const float4 sa1 = (kt & 1) ? aB1 : aA1;
    const uint4 sb0 = (kt & 1) ? bB0 : bA0;
    const uint4 sb1 = (kt & 1) ? bB1 : bA1;
    {
      bf16x8 av;
      av[0] = (short)f2bf(sa0.x); av[1] = (short)f2bf(sa0.y);
      av[2] = (short)f2bf(sa0.z); av[3] = (short)f2bf(sa0.w);
      av[4] = (short)f2bf(sa1.x); av[5] = (short)f2bf(sa1.y);
      av[6] = (short)f2bf(sa1.z); av[7] = (short)f2bf(sa1.w);
      *(bf16x8*)&Ac[ar * 32 + ((ac ^ ((ar >> 1) & 3)) << 3)] = av;
      *(uint4*)&Bc[tid * 16] = sb0;
      *(uint4*)&Bc[tid * 16 + 8] = sb1;
    }
    barrier_lds_only();   // LDS staged; in-flight global loads NOT drained
    if (kt + 2 < 8) {     // refill the just-consumed set: 2 iterations of slack
      const float4* ap = (const float4*)(abase + (kt + 2) * 32);
      const unsigned short* bp = Wp + ((size_t)((kt + 2) * 256 + n0)) * 32 + tid * 16;
      if (kt & 1) {
        aB0 = ap[0]; aB1 = ap[1];
        bB0 = ((const uint4*)bp)[0]; bB1 = ((const uint4*)bp)[1];
      } else {
        aA0 = ap[0]; aA1 = ap[1];
        bA0 = ((const uint4*)bp)[0]; bA1 = ((const uint4*)bp)[1];
      }
    }
    bf16x8 af[2], bq[4];
#pragma unroll
    for (int i = 0; i < 2; i++) {
      const int row = wr * 32 + i * 16 + l15;
      af[i] = *(const bf16x8*)&Ac[row * 32 + ((lc ^ ((row >> 1) & 3)) << 3)];
    }
#pragma unroll
    for (int q = 0; q < 4; q++) {
      const int col = wc * 64 + q * 16 + l15;
      bq[q] = *(const bf16x8*)&Bc[col * 32 + ((lc ^ ((col >> 1) & 3)) << 3)];
    }
#pragma unroll
    for (int i = 0; i < 2; i++)
#pragma unroll
      for (int q = 0; q < 4; q++)
        acc[i][q] = __builtin_amdgcn_mfma_f32_16x16x32_bf16(af[i], bq[q], acc[i][q], 0, 0, 0);
  }
  // ---- epilogue: bias + bf16 via per-wave strip, coalesced 16B stores ----
  __syncthreads();
  short* strip = (short*)lds + w * 2176;   // 32 rows x 68 shorts
  float bv[4];
#pragma unroll
  for (int q = 0; q < 4; q++) bv[q] = bias[n0 + wc * 64 + q * 16 + l15];
#pragma unroll
  for (int i = 0; i < 2; i++)
#pragma unroll
    for (int q = 0; q < 4; q++)
#pragma unroll
      for (int r = 0; r < 4; r++)
        strip[(i * 16 + lc * 4 + r) * 68 + q * 16 + l15] = (short)f2bf(acc[i][q][r] + bv[q]);
  __syncthreads();
#pragma unroll
  for (int p = 0; p < 4; p++) {
    const int row = p * 8 + (lane >> 3), c8 = lane & 7;
    const bf16x8 v = *(const bf16x8*)&strip[row * 68 + c8 * 8];
    const int grow = m0 + wr * 32 + row;
    if (grow < M)
      *(bf16x8*)(C + (size_t)grow * 256 + n0 + wc * 64 + c8 * 8) = v;
  }
}

// ---------------- shared GEMM body: 64x64 tile, packed B, pipelined (1 barrier/iter) ----------------
__device__ __forceinline__ void gemm_body(const void* Aptr, const float* A2,
                                          const unsigned short* __restrict__ Wp,
                                          const float* __restrict__ bias, void* Cptr,
                                          int M, int Nn, int K, float scale, int relu,
                                          int a_bf16, int out_bf16, int m0, int n0,
                                          short* As, short* Bs) {
  const int tid = threadIdx.x;
  const int lane = tid & 63, w = tid >> 6;
  const int wr = w >> 1, wc = w & 1;
  const int ar = tid >> 2, ac = tid & 3;
  const int l15 = lane & 15, lc = lane >> 4;
  const int arow = min(m0 + ar, M - 1);
  f32x4 acc[2][2] = {};
  float4 pa0, pa1, pc0, pc1; bf16x8 pav; uint4 pb;
  {
    if (a_bf16) {
      pav = *(const bf16x8*)((const unsigned short*)Aptr + (size_t)arow * K + ac * 8);
    } else {
      const float* ap_ = (const float*)Aptr + (size_t)arow * K + ac * 8;
      pa0 = ((const float4*)ap_)[0]; pa1 = ((const float4*)ap_)[1];
      if (A2) {
        const float* cp_ = A2 + (size_t)arow * K + ac * 8;
        pc0 = ((const float4*)cp_)[0]; pc1 = ((const float4*)cp_)[1];
      }
    }
    pb = *(const uint4*)(Wp + ((size_t)n0) * 32 + tid * 8);
  }
  for (int kt = 0; kt < K; kt += 32) {
    short* Ac = As + ((kt >> 5) & 1) * 2048;
    short* Bc = Bs + ((kt >> 5) & 1) * 2048;
    {
      bf16x8 av;
      if (a_bf16) {
        av = pav;
      } else {
        float4 a0 = pa0, a1 = pa1;
        if (A2) {
          a0.x += pc0.x; a0.y += pc0.y; a0.z += pc0.z; a0.w += pc0.w;
          a1.x += pc1.x; a1.y += pc1.y; a1.z += pc1.z; a1.w += pc1.w;
        }
        av[0] = (short)f2bf(a0.x); av[1] = (short)f2bf(a0.y);
        av[2] = (short)f2bf(a0.z); av[3] = (short)f2bf(a0.w);
        av[4] = (short)f2bf(a1.x); av[5] = (short)f2bf(a1.y);
        av[6] = (short)f2bf(a1.z); av[7] = (short)f2bf(a1.w);
      }
      *(bf16x8*)&Ac[ar * 32 + ((ac ^ ((ar >> 1) & 3)) << 3)] = av;
      *(uint4*)&Bc[tid * 8] = pb;
    }
    barrier_lds_only();
    if (kt + 32 < K) {   // prefetch next tile into regs
      if (a_bf16) {
        pav = *(const bf16x8*)((const unsigned short*)Aptr + (size_t)arow * K + kt + 32 + ac * 8);
      } else {
        const float* ap_ = (const float*)Aptr + (size_t)arow * K + kt + 32 + ac * 8;
        pa0 = ((const float4*)ap_)[0]; pa1 = ((const float4*)ap_)[1];
        if (A2) {
          const float* cp_ = A2 + (size_t)arow * K + kt + 32 + ac * 8;
          pc0 = ((const float4*)cp_)[0]; pc1 = ((const float4*)cp_)[1];
        }
      }
      pb = *(const uint4*)(Wp + ((size_t)(((kt >> 5) + 1) * Nn + n0)) * 32 + tid * 8);
    }
    bf16x8 af[2], bf[2];
#pragma unroll
    for (int i = 0; i < 2; i++) {
      const int row = wr * 32 + i * 16 + l15;
      af[i] = *(const bf16x8*)&Ac[row * 32 + ((lc ^ ((row >> 1) & 3)) << 3)];
      const int col = wc * 32 + i * 16 + l15;
      bf[i] = *(const bf16x8*)&Bc[col * 32 + ((lc ^ ((col >> 1) & 3)) << 3)];
    }
#pragma unroll
    for (int i = 0; i < 2; i++)
#pragma unroll
      for (int j = 0; j < 2; j++)
        acc[i][j] = __builtin_amdgcn_mfma_f32_16x16x32_bf16(af[i], bf[j], acc[i][j], 0, 0, 0);
  }
#pragma unroll
  for (int i = 0; i < 2; i++) {
    const int row0 = m0 + wr * 32 + i * 16 + lc * 4;
#pragma unroll
    for (int j = 0; j < 2; j++) {
      const int col = n0 + wc * 32 + j * 16 + l15;
      const float bv = bias[col];
#pragma unroll
      for (int r = 0; r < 4; r++) {
        const int row = row0 + r;
        if (row < M) {
          float v = (acc[i][j][r] + bv) * scale;
          if (relu) v = fmaxf(v, 0.f);
          if (out_bf16)
            ((unsigned short*)Cptr)[(size_t)row * Nn + col] = f2bf(v);
          else
            ((float*)Cptr)[(size_t)row * Nn + col] = v;
        }
      }
    }
  }
}

// ---------------- fused QKV projection: z selects Q/K/V; add(tgt,qpos) fused; bf16 out ----------------
__global__ __launch_bounds__(256) void gemm_qkv(const float* __restrict__ tgt,
                                                const float* __restrict__ qpos,
                                                const unsigned short* __restrict__ Wp,
                                                const float* __restrict__ bq_,
                                                const float* __restrict__ bk_,
                                                const float* __restrict__ bv_,
                                                unsigned short* Qb, unsigned short* Kb,
                                                unsigned short* Vb, float qscale) {
  __shared__ short As[2 * 2048];
  __shared__ short Bs[2 * 2048];
  const int z = blockIdx.z;
  const unsigned short* W = Wp + (z == 0 ? WP_Q : z == 1 ? WP_K : WP_V);
  const float* bias = (z == 0) ? bq_ : (z == 1) ? bk_ : bv_;
  unsigned short* C = (z == 0) ? Qb : (z == 1) ? Kb : Vb;
  const float* A2 = (z == 2) ? nullptr : qpos;
  gemm_body(tgt, A2, W, bias, C, MROW, DM, DM, (z == 0) ? qscale : 1.f, 0, 0, 1,
            blockIdx.y * 64, blockIdx.x * 64, As, Bs);
}

// ---------------- fused offset+attention-logit projection: add(x1,qpos) fused ----------------
__global__ __launch_bounds__(256) void gemm_offatt(const float* __restrict__ x1,
                                                   const float* __restrict__ qpos,
                                                   const unsigned short* __restrict__ Wp,
                                                   const float* __restrict__ b_off,
                                                   const float* __restrict__ b_att,
                                                   float* offb, float* attb) {
  const int z = blockIdx.z;
  if (z == 1 && blockIdx.x >= 2) return;
  __shared__ short As[2 * 2048];
  __shared__ short Bs[2 * 2048];
  const unsigned short* W = Wp + (z ? WP_ATT : WP_OFF);
  const float* bias = z ? b_att : b_off;
  float* C = z ? attb : offb;
  const int Nn = z ? 128 : 256;
  gemm_body(x1, qpos, W, bias, C, MROW, Nn, DM, 1.f, 0, 0, 0,
            blockIdx.y * 64, blockIdx.x * 64, As, Bs);
}

// ---------------- generic GEMM dispatch (packed B) ----------------
__global__ __launch_bounds__(256) void gemm_fused(const void* A, const unsigned short* Wp,
                                                  const float* bias, void* C, int M, int Nn,
                                                  int K, float scale, int relu, int a_bf16,
                                                  int out_bf16) {
  __shared__ short As[2 * 2048];
  __shared__ short Bs[2 * 2048];
  gemm_body(A, nullptr, Wp, bias, C, M, Nn, K, scale, relu, a_bf16, out_bf16,
            blockIdx.y * 64, blockIdx.x * 64, As, Bs);
}

// ---------------- MFMA flash attention (bf16 in/out, next-tile reg prefetch) ----------------
__global__ __launch_bounds__(256) void attn_mfma(const unsigned short* __restrict__ Qg,
                                                 const unsigned short* __restrict__ Kg,
                                                 const unsigned short* __restrict__ Vg,
                                                 unsigned short* __restrict__ O) {
  __shared__ short Ks[2048];
  __shared__ short Vt[2048];
  __shared__ short Pl[4096];
  const int tid = threadIdx.x;
  const int lane = tid & 63, w = tid >> 6;
  const int l15 = lane & 15, lc = lane >> 4;
  const int h = blockIdx.y, b = blockIdx.z;
  const int q0 = blockIdx.x * 64;
  char* KsB = (char*)Ks; char* VtB = (char*)Vt; char* PlB = (char*)Pl + w * 2048;

  bf16x8 qa;
  {
    const int qrow = min(q0 + w * 16 + l15, LQ - 1);
    qa = *(const bf16x8*)(Qg + ((size_t)(b * LQ + qrow)) * DM + h * DH + lc * 8);
  }
  f32x4 o0 = {0.f, 0.f, 0.f, 0.f}, o1 = {0.f, 0.f, 0.f, 0.f};
  float mrow[4], lrow[4];
#pragma unroll
  for (int r = 0; r < 4; r++) { mrow[r] = -1e30f; lrow[r] = 0.f; }
  const int skey = tid >> 2, sq = tid & 3;

  // preload tile 0
  bf16x8 kb, vv;
  {
    const int kr = min(skey, LQ - 1);
    kb = *(const bf16x8*)(Kg + ((size_t)(b * LQ + kr)) * DM + h * DH + sq * 8);
    vv = *(const bf16x8*)(Vg + ((size_t)(b * LQ + kr)) * DM + h * DH + sq * 8);
  }
  for (int kt = 0; kt < LQ; kt += 64) {
    __syncthreads();   // prev tile's LDS reads done
    {
      *(bf16x8*)(KsB + ((skey * 64 + sq * 16) ^ ((skey & 7) << 4))) = kb;
#pragma unroll
      for (int j = 0; j < 8; j++) {
        const int dh = sq * 8 + j;
        const int qz = ((dh & 7) ^ (((dh >> 3) & 3) << 1)) << 4;
        *(short*)(VtB + ((dh * 128 + skey * 2) ^ qz)) = (short)vv[j];
      }
    }
    __syncthreads();   // staging visible
    if (kt + 64 < LQ) {   // prefetch next K/V tile; hides under S/softmax/PV below
      const int kr = min(kt + 64 + skey, LQ - 1);
      kb = *(const bf16x8*)(Kg + ((size_t)(b * LQ + kr)) * DM + h * DH + sq * 8);
      vv = *(const bf16x8*)(Vg + ((size_t)(b * LQ + kr)) * DM + h * DH + sq * 8);
    }
    f32x4 s[4];
#pragma unroll
    for (int cb = 0; cb < 4; cb++) {
      const int key = cb * 16 + l15;
      const bf16x8 kf = *(const bf16x8*)(KsB + ((key * 64 + lc * 16) ^ ((key & 7) << 4)));
      const f32x4 z = {0.f, 0.f, 0.f, 0.f};
      s[cb] = __builtin_amdgcn_mfma_f32_16x16x32_bf16(qa, kf, z, 0, 0, 0);
    }
#pragma unroll
    for (int cb = 0; cb < 4; cb++)
      if (kt + cb * 16 + l15 >= LQ) {
        s[cb][0] = -1e30f; s[cb][1] = -1e30f; s[cb][2] = -1e30f; s[cb][3] = -1e30f;
      }
    float tm[4], fs[4], ps[4];
#pragma unroll
    for (int r = 0; r < 4; r++)
      tm[r] = fmaxf(fmaxf(s[0][r], s[1][r]), fmaxf(s[2][r], s[3][r]));
#pragma unroll
    for (int msk = 1; msk <= 8; msk <<= 1)
#pragma unroll
      for (int r = 0; r < 4; r++) tm[r] = fmaxf(tm[r], __shfl_xor(tm[r], msk));
#pragma unroll
    for (int r = 0; r < 4; r++) {
      const float nm = fmaxf(mrow[r], tm[r]);
      fs[r] = __expf(mrow[r] - nm);
      mrow[r] = nm;
    }
#pragma unroll
    for (int cb = 0; cb < 4; cb++)
#pragma unroll
      for (int r = 0; r < 4; r++) s[cb][r] = __expf(s[cb][r] - mrow[r]);
#pragma unroll
    for (int r = 0; r < 4; r++) ps[r] = (s[0][r] + s[1][r]) + (s[2][r] + s[3][r]);
#pragma unroll
    for (int msk = 1; msk <= 8; msk <<= 1)
#pragma unroll
      for (int r = 0; r < 4; r++) ps[r] += __shfl_xor(ps[r], msk);
#pragma unroll
    for (int r = 0; r < 4; r++) {
      lrow[r] = lrow[r] * fs[r] + ps[r];
      o0[r] *= fs[r]; o1[r] *= fs[r];
    }
#pragma unroll
    for (int cb = 0; cb < 4; cb++)
#pragma unroll
      for (int r = 0; r < 4; r++) {
        const int row = lc * 4 + r, col = cb * 16 + l15;
        *(short*)(PlB + ((row * 128 + col * 2) ^ ((row & 7) << 4))) = (short)f2bf(s[cb][r]);
      }
#pragma unroll
    for (int ks2 = 0; ks2 < 2; ks2++) {
      const int koff2 = (ks2 * 32 + lc * 8) * 2;
      const bf16x8 pa = *(const bf16x8*)(PlB + ((l15 * 128 + koff2) ^ ((l15 & 7) << 4)));
      {
        const int dh = l15;
        const int qz = ((dh & 7) ^ (((dh >> 3) & 3) << 1)) << 4;
        const bf16x8 vf = *(const bf16x8*)(VtB + ((dh * 128 + koff2) ^ qz));
        o0 = __builtin_amdgcn_mfma_f32_16x16x32_bf16(pa, vf, o0, 0, 0, 0);
      }
      {
        const int dh = 16 + l15;
        const int qz = ((dh & 7) ^ (((dh >> 3) & 3) << 1)) << 4;
        const bf16x8 vf = *(const bf16x8*)(VtB + ((dh * 128 + koff2) ^ qz));
        o1 = __builtin_amdgcn_mfma_f32_16x16x32_bf16(pa, vf, o1, 0, 0, 0);
      }
    }
  }
#pragma unroll
  for (int r = 0; r < 4; r++) {
    const int qrow = q0 + w * 16 + lc * 4 + r;
    if (qrow < LQ) {
      const float inv = 1.f / lrow[r];
      unsigned short* op = O + ((size_t)(b * LQ + qrow)) * DM + h * DH;
      op[l15] = f2bf(o0[r] * inv);
      op[16 + l15] = f2bf(o1[r] * inv);
    }
  }
}

// ---------------- MS-deform sampling: 8 threads per (b,q,h), 4 channels each; bf16 out ----------------
__global__ __launch_bounds__(256) void sample_kernel(const unsigned short* __restrict__ value,
                                                     const float* __restrict__ ref,
                                                     const float* __restrict__ off,
                                                     const float* __restrict__ att,
                                                     unsigned short* __restrict__ out) {
  const int t = blockIdx.x * 256 + threadIdx.x;   // < NB*LQ*NH*8 = 460800
  const int d4 = t & 7;
  const int h = (t >> 3) & 7;
  const int qb = t >> 6;                           // b*LQ + q
  const int b = qb / LQ;
  const int HLs[4] = {100, 50, 25, 13};
  const int STs[4] = {0, 10000, 12500, 13125};
  const float* rp = ref + (size_t)qb * (NL * 2);
  const float* op = off + (size_t)qb * DM + h * (NL * NP * 2);
  const float* ap = att + (size_t)qb * (NH * NL * NP) + h * (NL * NP);
  const unsigned short* vb = value + (size_t)b * LIN * DM + h * DH + d4 * 4;

  float aw[16];
#pragma unroll
  for (int i = 0; i < 4; i++) {
    const float4 a4 = ((const float4*)ap)[i];
    aw[4 * i] = a4.x; aw[4 * i + 1] = a4.y; aw[4 * i + 2] = a4.z; aw[4 * i + 3] = a4.w;
  }
  float am = aw[0];
#pragma unroll
  for (int i = 1; i < 16; i++) am = fmaxf(am, aw[i]);
  float asum = 0.f;
#pragma unroll
  for (int i = 0; i < 16; i++) { aw[i] = __expf(aw[i] - am); asum += aw[i]; }
  const float ainv = 1.f / asum;

  float acc[4] = {};
#pragma unroll
  for (int l = 0; l < NL; l++) {
    const int Hl = HLs[l], Wl = HLs[l], st = STs[l];
    const float rx = rp[l * 2], ry = rp[l * 2 + 1];
#pragma unroll
    for (int p = 0; p < NP; p++) {
      const float2 o2 = ((const float2*)op)[l * NP + p];
      const float a = aw[l * NP + p] * ainv;
      const float locx = rx + o2.x / (float)Wl;
      const float locy = ry + o2.y / (float)Hl;
      const float x = locx * (float)Wl - 0.5f;
      const float y = locy * (float)Hl - 0.5f;
      const float xf = floorf(x), yf = floorf(y);
      const float fx = x - xf, fy = y - yf;
      const int x0 = (int)xf, y0 = (int)yf;
      const int x1 = x0 + 1, y1 = y0 + 1;
      const float vx0 = (x0 >= 0 && x0 < Wl) ? 1.f : 0.f;
      const float vx1 = (x1 >= 0 && x1 < Wl) ? 1.f : 0.f;
      const float vy0 = (y0 >= 0 && y0 < Hl) ? 1.f : 0.f;
      const float vy1 = (y1 >= 0 && y1 < Hl) ? 1.f : 0.f;
      const int cx0 = min(max(x0, 0), Wl - 1), cx1 = min(max(x1, 0), Wl - 1);
      const int cy0 = min(max(y0, 0), Hl - 1), cy1 = min(max(y1, 0), Hl - 1);
      const float w00 = a * (1.f - fx) * (1.f - fy) * vx0 * vy0;
      const float w10 = a * fx * (1.f - fy) * vx1 * vy0;
      const float w01 = a * (1.f - fx) * fy * vx0 * vy1;
      const float w11 = a * fx * fy * vx1 * vy1;
      const unsigned short* r0 = vb + (size_t)(st + cy0 * Wl) * DM;
      const unsigned short* r1 = vb + (size_t)(st + cy1 * Wl) * DM;
      const uint2 g00 = *(const uint2*)(r0 + (size_t)cx0 * DM);
      const uint2 g10 = *(const uint2*)(r0 + (size_t)cx1 * DM);
      const uint2 g01 = *(const uint2*)(r1 + (size_t)cx0 * DM);
      const uint2 g11 = *(const uint2*)(r1 + (size_t)cx1 * DM);
      const unsigned u00[2] = {g00.x, g00.y};
      const unsigned u10[2] = {g10.x, g10.y};
      const unsigned u01[2] = {g01.x, g01.y};
      const unsigned u11[2] = {g11.x, g11.y};
#pragma unroll
      for (int i = 0; i < 2; i++) {
        acc[2 * i]     += w00 * __uint_as_float(u00[i] << 16) + w10 * __uint_as_float(u10[i] << 16)
                        + w01 * __uint_as_float(u01[i] << 16) + w11 * __uint_as_float(u11[i] << 16);
        acc[2 * i + 1] += w00 * __uint_as_float(u00[i] & 0xFFFF0000u) + w10 * __uint_as_float(u10[i] & 0xFFFF0000u)
                        + w01 * __uint_as_float(u01[i] & 0xFFFF0000u) + w11 * __uint_as_float(u11[i] & 0xFFFF0000u);
      }
    }
  }
  uint2 ov;
  ov.x = (unsigned)f2bf(acc[0]) | ((unsigned)f2bf(acc[1]) << 16);
  ov.y = (unsigned)f2bf(acc[2]) | ((unsigned)f2bf(acc[3]) << 16);
  *(uint2*)(out + (size_t)t * 4) = ov;
}

// ---------------- fused residual-add + LayerNorm, 4 rows per block (1 wave/row) ----------------
__global__ __launch_bounds__(256) void ln_kernel(const float* __restrict__ A,
                                                 const float* __restrict__ R,
                                                 const float* __restrict__ g,
                                                 const float* __restrict__ be,
                                                 float* __restrict__ out) {
  const int row = blockIdx.x * 4 + (threadIdx.x >> 6);
  const int t = threadIdx.x & 63;
  const float4 va = ((const float4*)(A + (size_t)row * DM))[t];
  const float4 vr = ((const float4*)(R + (size_t)row * DM))[t];
  const float x0 = va.x + vr.x, x1 = va.y + vr.y, x2 = va.z + vr.z, x3 = va.w + vr.w;
  float s = x0 + x1 + x2 + x3;
  float ss = x0 * x0 + x1 * x1 + x2 * x2 + x3 * x3;
#pragma unroll
  for (int o = 1; o < 64; o <<= 1) { s += __shfl_xor(s, o); ss += __shfl_xor(ss, o); }
  const float mean = s * (1.f / DM);
  const float var = ss * (1.f / DM) - mean * mean;
  const float rstd = rsqrtf(var + 1e-5f);
  const float4 vg = ((const float4*)g)[t];
  const float4 vb = ((const float4*)be)[t];
  float4 o4;
  o4.x = (x0 - mean) * rstd * vg.x + vb.x;
  o4.y = (x1 - mean) * rstd * vg.y + vb.y;
  o4.z = (x2 - mean) * rstd * vg.z + vb.z;
  o4.w = (x3 - mean) * rstd * vg.w + vb.w;
  ((float4*)(out + (size_t)row * DM))[t] = o4;
}

extern "C" void kernel_launch(void* const* d_in, const int* in_sizes, int n_in,
                              void* d_out, int out_size, void* d_ws, size_t ws_size,
                              hipStream_t stream) {
  const float* tgt  = (const float*)d_in[1];
  const float* qpos = (const float*)d_in[2];
  const float* ref  = (const float*)d_in[3];
  const float* src  = (const float*)d_in[4];
  const float* wq = (const float*)d_in[8];  const float* bq = (const float*)d_in[9];
  const float* wk = (const float*)d_in[10]; const float* bk = (const float*)d_in[11];
  const float* wv = (const float*)d_in[12]; const float* bv = (const float*)d_in[13];
  const float* wo = (const float*)d_in[14]; const float* bo = (const float*)d_in[15];
  const float* w_val = (const float*)d_in[16]; const float* b_val = (const float*)d_in[17];
  const float* w_off = (const float*)d_in[18]; const float* b_off = (const float*)d_in[19];
  const float* w_att = (const float*)d_in[20]; const float* b_att = (const float*)d_in[21];
  const float* w_out = (const float*)d_in[22]; const float* b_out = (const float*)d_in[23];
  const float* ln1g = (const float*)d_in[24]; const float* ln1b = (const float*)d_in[25];
  const float* ln2g = (const float*)d_in[26]; const float* ln2b = (const float*)d_in[27];
  const float* ln3g = (const float*)d_in[28]; const float* ln3b = (const float*)d_in[29];
  const float* w1 = (const float*)d_in[30]; const float* b1 = (const float*)d_in[31];
  const float* w2 = (const float*)d_in[32]; const float* b2 = (const float*)d_in[33];

  const size_t S = (size_t)MROW * DM;
  const size_t VAL_F = (size_t)NVAL * DM;
  float* ws = (float*)d_ws;
  float* value = ws;                 // bf16: floats [0, VAL_F/2)
  unsigned short* wp = (unsigned short*)(ws + VAL_F / 2);  // ~2 MB packed weights
  float* B0   = ws + VAL_F;
  unsigned short* Qb = (unsigned short*)(B0 + 1 * S);   // bf16
  unsigned short* Kb = (unsigned short*)(B0 + 2 * S);   // bf16
  unsigned short* Vb = (unsigned short*)(B0 + 3 * S);   // bf16
  unsigned short* Ob = (unsigned short*)(B0 + 4 * S);   // bf16
  float* tmp  = B0 + 5 * S;
  float* x1   = B0 + 0 * S;
  float* offb = B0 + 2 * S;
  float* attb = B0 + 3 * S;
  unsigned short* samp = (unsigned short*)(B0 + 4 * S); // bf16 (Ob dead by then)
  float* x2   = B0 + 6 * S;
  unsigned short* hffn = (unsigned short*)(B0 + 1 * S); // bf16, spans [1S,3S)

  const float qscale = 0.17677669529663687f;  // 1/sqrt(32)
  const dim3 blk(256);
  const dim3 gQ(DM / 64, (MROW + 63) / 64);            // (4,113)

  // ---- weight pack (one dispatch, all 10 matrices) ----
  pack_all<<<dim3(WP_TOT / 256), blk, 0, stream>>>(w_val, wq, wk, wv, wo, w_off, w_att,
                                                   w_out, w1, w2, wp);

  // ---- self-attention ----
  gemm_qkv<<<dim3(4, 113, 3), blk, 0, stream>>>(tgt, qpos, wp, bq, bk, bv,
                                                Qb, Kb, Vb, qscale);
  attn_mfma<<<dim3((LQ + 63) / 64, NH, NB), blk, 0, stream>>>(Qb, Kb, Vb, Ob);
  gemm_fused<<<gQ, blk, 0, stream>>>(Ob, wp + WP_O, bo, tmp, MROW, DM, DM, 1.f, 0, 1, 0);
  ln_kernel<<<dim3(MROW / 4), blk, 0, stream>>>(tmp, tgt, ln2g, ln2b, x1);

  // ---- deformable cross-attention ----
  value_gemm9<<<dim3(GVAL2), blk, 0, stream>>>(src, wp + WP_VAL, b_val,
                                               (unsigned short*)value, NVAL);
  gemm_offatt<<<dim3(4, 113, 2), blk, 0, stream>>>(x1, qpos, wp, b_off, b_att, offb, attb);
  sample_kernel<<<dim3((MROW * NH * 8) / 256), blk, 0, stream>>>(
      (const unsigned short*)value, ref, offb, attb, samp);
  gemm_fused<<<gQ, blk, 0, stream>>>(samp, wp + WP_OUT, b_out, tmp, MROW, DM, DM,
                                     1.f, 0, 1, 0);
  ln_kernel<<<dim3(MROW / 4), blk, 0, stream>>>(tmp, x1, ln1g, ln1b, x2);

  // ---- FFN ----
  gemm_fused<<<dim3(DFFN / 64, 113), blk, 0, stream>>>(x2, wp + WP_W1, b1, hffn, MROW,
                                                       DFFN, DM, 1.f, 1, 0, 1);
  gemm_fused<<<gQ, blk, 0, stream>>>(hffn, wp + WP_W2, b2, tmp, MROW, DM, DFFN,
                                     1.f, 0, 1, 0);
  ln_kernel<<<dim3(MROW / 4), blk, 0, stream>>>(tmp, x2, ln3g, ln3b, (float*)d_out);
}